// Round 3
// baseline (2705.886 us; speedup 1.0000x reference)
//
#include <hip/hip_runtime.h>
#include <cmath>

namespace {

constexpr int L   = 1024;
constexpr int D   = 1024;
constexpr int DFF = 4096;
constexpr int NL  = 3;
constexpr int NH  = 16;
constexpr int DH  = 64;
constexpr long LD = (long)L * D;   // 1048576

typedef __attribute__((ext_vector_type(8))) short bf16x8;  // 8 bf16 (4 VGPRs)
typedef __attribute__((ext_vector_type(4))) float f32x4;   // MFMA C/D

// Split fp32 into hi/lo bf16 (truncation split)
__device__ inline void split1(float f, unsigned short& h, unsigned short& l)
{
    unsigned u = __float_as_uint(f);
    h = (unsigned short)(u >> 16);
    float hf = __uint_as_float(u & 0xffff0000u);
    l = (unsigned short)(__float_as_uint(f - hf) >> 16);
}

// ---------------------------------------------------------------------------
// Weight repack: fp32 [K x N] (ldw, batch sW) -> fragment-ordered hi/lo bf16.
// Chunk = (k32-block, n16-block) = 2KB: hi[lane][8] at lane*8, lo at 512+lane*8,
// lane = (n%16) + ((k%32)/8)*16  == exactly the 16x16x32 MFMA B-fragment layout.
// One wave handles one chunk (8 elems/thread); block = 4 chunks.
// ---------------------------------------------------------------------------
__global__ __launch_bounds__(256)
void repack_w(const float* __restrict__ W, int ldw, long sW,
              unsigned short* __restrict__ out, long sOut, int Np)
{
    const int t    = threadIdx.x;
    const int lane = t & 63;
    const int c    = blockIdx.x * 4 + (t >> 6);
    const int z    = blockIdx.y;
    const int nch  = Np >> 4;
    const int k0   = (c / nch) * 32 + ((lane >> 4) << 3);
    const int n    = (c % nch) * 16 + (lane & 15);
    const float* Wz = W + (long)z * sW + n;
    unsigned short* oz = out + (long)z * sOut + (long)c * 1024 + (lane << 3);
    unsigned short h[8], l[8];
#pragma unroll
    for (int e = 0; e < 8; ++e)
        split1(Wz[(long)(k0 + e) * ldw], h[e], l[e]);
    *(ushort4*)(oz)       = *(ushort4*)&h[0];
    *(ushort4*)(oz + 4)   = *(ushort4*)&h[4];
    *(ushort4*)(oz + 512) = *(ushort4*)&l[0];
    *(ushort4*)(oz + 516) = *(ushort4*)&l[4];
}

// ---------------------------------------------------------------------------
// Packed-B MFMA GEMM: C[z] = act(alpha * A[z]@B[z] + bias[z])
//  A: fp32 [M x K] row-major, staged through LDS as hi/lo bf16.
//  B: pre-packed fragment-order hi/lo bf16 (repack_w), read straight from
//     global -> registers. No LDS for B at all.
// ---------------------------------------------------------------------------
template<int BM, int BN, int ACT>
__global__ __launch_bounds__(256)
void gemm_mfma_pb(const float* __restrict__ A, int lda, long sA,
                  const unsigned short* __restrict__ Bp, int Np, long sBp,
                  float* __restrict__ C, int ldc, long sC,
                  const float* __restrict__ bias, long sBias,
                  int K, float alpha)
{
    constexpr int BK = 32;
    constexpr int PK = 40;
    constexpr int FM = BM / 32;
    constexpr int FN = BN / 32;
    constexpr int NA = BM / 32;

    __shared__ unsigned short Ah[BM][PK], Al[BM][PK];

    const int tid  = threadIdx.x;
    const int lane = tid & 63;
    const int wave = tid >> 6;
    const int wm   = (wave >> 1) * (BM / 2);
    const int wn   = (wave & 1)  * (BN / 2);
    const int lr   = lane & 15;
    const int ko   = (lane >> 4) * 8;

    const float* Abase = A + (long)blockIdx.z * sA;
    const unsigned short* Bb = Bp + (long)blockIdx.z * sBp;
    float* Cbase = C + (long)blockIdx.z * sC;
    const int n0  = blockIdx.x * BN;
    const int m0  = blockIdx.y * BM;
    const int nch = Np >> 4;
    const int cb  = (n0 + wn) >> 4;

    f32x4 acc[FM][FN];
#pragma unroll
    for (int i = 0; i < FM; ++i)
#pragma unroll
        for (int j = 0; j < FN; ++j) acc[i][j] = f32x4{0.f, 0.f, 0.f, 0.f};

    const int akq = tid & 7;
    const int amr = tid >> 3;

    auto loadA = [&](int kt, float4* pa) {
#pragma unroll
        for (int r = 0; r < NA; ++r)
            pa[r] = *(const float4*)(Abase + (long)(m0 + r * 32 + amr) * lda + kt + akq * 4);
    };
    auto storeA = [&](const float4* pa) {
#pragma unroll
        for (int r = 0; r < NA; ++r) {
            ushort4 h, l;
            split1(pa[r].x, h.x, l.x); split1(pa[r].y, h.y, l.y);
            split1(pa[r].z, h.z, l.z); split1(pa[r].w, h.w, l.w);
            *(ushort4*)&Ah[r * 32 + amr][akq * 4] = h;
            *(ushort4*)&Al[r * 32 + amr][akq * 4] = l;
        }
    };
    auto loadB = [&](int kt, bf16x8* h, bf16x8* l) {
        const unsigned short* p = Bb + ((long)(kt >> 5) * nch + cb) * 1024 + (lane << 3);
#pragma unroll
        for (int ni = 0; ni < FN; ++ni) {
            h[ni] = *(const bf16x8*)(p + ni * 1024);
            l[ni] = *(const bf16x8*)(p + ni * 1024 + 512);
        }
    };

    float4 pa[NA];
    bf16x8 bh[FN], bl[FN];
    loadA(0, pa); loadB(0, bh, bl);

    for (int kt = 0; kt < K; kt += BK) {
        storeA(pa);
        __syncthreads();

        const bool more = kt + BK < K;
        float4 na[NA];
        bf16x8 nh[FN], nl[FN];
        if (more) { loadA(kt + BK, na); loadB(kt + BK, nh, nl); }

        bf16x8 ah[FM], al[FM];
#pragma unroll
        for (int mi = 0; mi < FM; ++mi) {
            ah[mi] = *(const bf16x8*)&Ah[wm + mi * 16 + lr][ko];
            al[mi] = *(const bf16x8*)&Al[wm + mi * 16 + lr][ko];
        }
#pragma unroll
        for (int mi = 0; mi < FM; ++mi)
#pragma unroll
            for (int ni = 0; ni < FN; ++ni) {
                acc[mi][ni] = __builtin_amdgcn_mfma_f32_16x16x32_bf16(
                    ah[mi], bh[ni], acc[mi][ni], 0, 0, 0);
                acc[mi][ni] = __builtin_amdgcn_mfma_f32_16x16x32_bf16(
                    ah[mi], bl[ni], acc[mi][ni], 0, 0, 0);
                acc[mi][ni] = __builtin_amdgcn_mfma_f32_16x16x32_bf16(
                    al[mi], bh[ni], acc[mi][ni], 0, 0, 0);
            }
        __syncthreads();

        if (more) {
#pragma unroll
            for (int r = 0; r < NA; ++r) pa[r] = na[r];
#pragma unroll
            for (int r = 0; r < FN; ++r) { bh[r] = nh[r]; bl[r] = nl[r]; }
        }
    }

    float bv[FN];
#pragma unroll
    for (int ni = 0; ni < FN; ++ni)
        bv[ni] = bias ? bias[(long)blockIdx.z * sBias + n0 + wn + ni * 16 + lr] : 0.f;
    const int cr = (lane >> 4) * 4;
#pragma unroll
    for (int mi = 0; mi < FM; ++mi)
#pragma unroll
        for (int ni = 0; ni < FN; ++ni) {
#pragma unroll
            for (int r = 0; r < 4; ++r) {
                float t = acc[mi][ni][r] * alpha + bv[ni];
                if (ACT == 1) t = fmaxf(t, 0.f);
                else if (ACT == 2) t = tanhf(t);
                Cbase[(long)(m0 + wm + mi * 16 + cr + r) * ldc
                      + n0 + wn + ni * 16 + lr] = t;
            }
        }
}

// ---------------------------------------------------------------------------
// Dynamic-B split-bf16 MFMA GEMM (kept for QK^T and PV where B is computed).
// ---------------------------------------------------------------------------
template<int BM, int BN, int ACT, bool BT>
__global__ __launch_bounds__(256)
void gemm_mfma(const float* __restrict__ A, int lda, long sA,
               const float* __restrict__ B, int ldb, long sB,
               float* __restrict__ C, int ldc, long sC,
               const float* __restrict__ bias, long sBias,
               int K, float alpha)
{
    constexpr int BK = 32;
    constexpr int PK = 40;
    constexpr int FM = BM / 32;
    constexpr int FN = BN / 32;
    constexpr int NA = BM / 32;
    constexpr int KQP = 256 / BN;
    constexpr int NB = BT ? (BN / 32) : (BK / (4 * KQP));

    __shared__ unsigned short Ah[BM][PK], Al[BM][PK];
    __shared__ unsigned short Bh[BN][PK], Bl[BN][PK];

    const int tid  = threadIdx.x;
    const int lane = tid & 63;
    const int wave = tid >> 6;
    const int wm   = (wave >> 1) * (BM / 2);
    const int wn   = (wave & 1)  * (BN / 2);
    const int lr   = lane & 15;
    const int ko   = (lane >> 4) * 8;

    const float* Abase = A + (long)blockIdx.z * sA;
    const float* Bbase = B + (long)blockIdx.z * sB;
    float*       Cbase = C + (long)blockIdx.z * sC;
    const int n0 = blockIdx.x * BN;
    const int m0 = blockIdx.y * BM;

    f32x4 acc[FM][FN];
#pragma unroll
    for (int i = 0; i < FM; ++i)
#pragma unroll
        for (int j = 0; j < FN; ++j) acc[i][j] = f32x4{0.f, 0.f, 0.f, 0.f};

    const int akq = tid & 7;
    const int amr = tid >> 3;
    const int nn  = tid % BN;
    const int kq0 = tid / BN;

    auto loadA = [&](int kt, float4* pa) {
#pragma unroll
        for (int r = 0; r < NA; ++r)
            pa[r] = *(const float4*)(Abase + (long)(m0 + r * 32 + amr) * lda + kt + akq * 4);
    };
    auto loadB = [&](int kt, float4* pb) {
        if constexpr (BT) {
#pragma unroll
            for (int r = 0; r < NB; ++r)
                pb[r] = *(const float4*)(Bbase + (long)(n0 + r * 32 + amr) * ldb + kt + akq * 4);
        } else {
#pragma unroll
            for (int r = 0; r < NB; ++r) {
                const int k = (r * KQP + kq0) * 4;
                pb[r].x = Bbase[(long)(kt + k + 0) * ldb + n0 + nn];
                pb[r].y = Bbase[(long)(kt + k + 1) * ldb + n0 + nn];
                pb[r].z = Bbase[(long)(kt + k + 2) * ldb + n0 + nn];
                pb[r].w = Bbase[(long)(kt + k + 3) * ldb + n0 + nn];
            }
        }
    };
    auto storeA = [&](const float4* pa) {
#pragma unroll
        for (int r = 0; r < NA; ++r) {
            ushort4 h, l;
            split1(pa[r].x, h.x, l.x); split1(pa[r].y, h.y, l.y);
            split1(pa[r].z, h.z, l.z); split1(pa[r].w, h.w, l.w);
            *(ushort4*)&Ah[r * 32 + amr][akq * 4] = h;
            *(ushort4*)&Al[r * 32 + amr][akq * 4] = l;
        }
    };
    auto storeB = [&](const float4* pb) {
        if constexpr (BT) {
#pragma unroll
            for (int r = 0; r < NB; ++r) {
                ushort4 h, l;
                split1(pb[r].x, h.x, l.x); split1(pb[r].y, h.y, l.y);
                split1(pb[r].z, h.z, l.z); split1(pb[r].w, h.w, l.w);
                *(ushort4*)&Bh[r * 32 + amr][akq * 4] = h;
                *(ushort4*)&Bl[r * 32 + amr][akq * 4] = l;
            }
        } else {
#pragma unroll
            for (int r = 0; r < NB; ++r) {
                const int k = (r * KQP + kq0) * 4;
                ushort4 h, l;
                split1(pb[r].x, h.x, l.x); split1(pb[r].y, h.y, l.y);
                split1(pb[r].z, h.z, l.z); split1(pb[r].w, h.w, l.w);
                *(ushort4*)&Bh[nn][k] = h;
                *(ushort4*)&Bl[nn][k] = l;
            }
        }
    };

    float4 pa[NA], pb[NB];
    loadA(0, pa); loadB(0, pb);

    for (int kt = 0; kt < K; kt += BK) {
        storeA(pa);
        storeB(pb);
        __syncthreads();

        const bool more = kt + BK < K;
        float4 na[NA], nb[NB];
        if (more) { loadA(kt + BK, na); loadB(kt + BK, nb); }

        bf16x8 ah[FM], al[FM], bh[FN], bl[FN];
#pragma unroll
        for (int mi = 0; mi < FM; ++mi) {
            ah[mi] = *(const bf16x8*)&Ah[wm + mi * 16 + lr][ko];
            al[mi] = *(const bf16x8*)&Al[wm + mi * 16 + lr][ko];
        }
#pragma unroll
        for (int ni = 0; ni < FN; ++ni) {
            bh[ni] = *(const bf16x8*)&Bh[wn + ni * 16 + lr][ko];
            bl[ni] = *(const bf16x8*)&Bl[wn + ni * 16 + lr][ko];
        }
#pragma unroll
        for (int mi = 0; mi < FM; ++mi)
#pragma unroll
            for (int ni = 0; ni < FN; ++ni) {
                acc[mi][ni] = __builtin_amdgcn_mfma_f32_16x16x32_bf16(
                    ah[mi], bh[ni], acc[mi][ni], 0, 0, 0);
                acc[mi][ni] = __builtin_amdgcn_mfma_f32_16x16x32_bf16(
                    ah[mi], bl[ni], acc[mi][ni], 0, 0, 0);
                acc[mi][ni] = __builtin_amdgcn_mfma_f32_16x16x32_bf16(
                    al[mi], bh[ni], acc[mi][ni], 0, 0, 0);
            }
        __syncthreads();

        if (more) {
#pragma unroll
            for (int r = 0; r < NA; ++r) pa[r] = na[r];
#pragma unroll
            for (int r = 0; r < NB; ++r) pb[r] = nb[r];
        }
    }

    float bv[FN];
#pragma unroll
    for (int ni = 0; ni < FN; ++ni)
        bv[ni] = bias ? bias[(long)blockIdx.z * sBias + n0 + wn + ni * 16 + lr] : 0.f;
    const int cr = (lane >> 4) * 4;
#pragma unroll
    for (int mi = 0; mi < FM; ++mi)
#pragma unroll
        for (int ni = 0; ni < FN; ++ni) {
#pragma unroll
            for (int r = 0; r < 4; ++r) {
                float t = acc[mi][ni][r] * alpha + bv[ni];
                if (ACT == 1) t = fmaxf(t, 0.f);
                else if (ACT == 2) t = tanhf(t);
                Cbase[(long)(m0 + wm + mi * 16 + cr + r) * ldc
                      + n0 + wn + ni * 16 + lr] = t;
            }
        }
}

// ---------------------------------------------------------------------------
__global__ void add_pe_kernel(const float* __restrict__ src, float* __restrict__ x)
{
    long idx = (long)blockIdx.x * 256 + threadIdx.x;   // < LD
    int pos = (int)(idx >> 10);
    int d   = (int)(idx & 1023);
    float expnt = (float)(d & ~1) * (1.0f / (float)D);
    float denom = powf(10000.0f, expnt);
    float ang   = (float)pos / denom;
    float pe    = (d & 1) ? cosf(ang) : sinf(ang);
    float v = src[idx] + pe;
    x[idx]          = v;
    x[LD + idx]     = v;
    x[2 * LD + idx] = v;
}

// ---------------------------------------------------------------------------
__global__ __launch_bounds__(256)
void softmax_mask_kernel(float* __restrict__ S, const int* __restrict__ utt,
                         const int* __restrict__ spk, const int* __restrict__ winp,
                         int branch)
{
    __shared__ float red[8];
    const int i   = blockIdx.x;
    const int h   = blockIdx.y;
    const int tid = threadIdx.x;
    float* row = S + ((long)h * L + i) * L;
    const int window = winp[0];
    const int utti   = utt[i];
    const int spki   = spk[i];
    const int j0 = tid * 4;

    float4 sv = *(float4*)(row + j0);
    float s[4] = {sv.x, sv.y, sv.z, sv.w};
#pragma unroll
    for (int c = 0; c < 4; ++c) {
        int j = j0 + c;
        int dd = j - i;
        bool win  = (dd <= window) && (-dd <= window);
        bool base = win && (utti > 0) && (utt[j] > 0);
        bool same = (spk[j] == spki);
        bool keep = (branch == 0) ? base
                  : (branch == 1) ? (base && same)
                  : (base && (!same || (j == i)));
        s[c] += keep ? 0.f : -1e9f;
    }
    float mx = fmaxf(fmaxf(s[0], s[1]), fmaxf(s[2], s[3]));
    for (int off = 32; off; off >>= 1) mx = fmaxf(mx, __shfl_xor(mx, off));
    if ((tid & 63) == 0) red[tid >> 6] = mx;
    __syncthreads();
    mx = fmaxf(fmaxf(red[0], red[1]), fmaxf(red[2], red[3]));
    __syncthreads();

    float e[4]; float sum = 0.f;
#pragma unroll
    for (int c = 0; c < 4; ++c) { e[c] = expf(s[c] - mx); sum += e[c]; }
    for (int off = 32; off; off >>= 1) sum += __shfl_xor(sum, off);
    if ((tid & 63) == 0) red[tid >> 6] = sum;
    __syncthreads();
    float inv = 1.f / (red[0] + red[1] + red[2] + red[3]);

    float4 o = {e[0] * inv, e[1] * inv, e[2] * inv, e[3] * inv};
    *(float4*)(row + j0) = o;
}

// ---------------------------------------------------------------------------
__global__ __launch_bounds__(256)
void ln_kernel(const float* __restrict__ x, const float* __restrict__ r,
               const float* __restrict__ g, const float* __restrict__ b,
               float* __restrict__ out, long paramStride)
{
    __shared__ float red[8];
    const int row = blockIdx.x;
    const int grp = row >> 10;
    const int tid = threadIdx.x;
    const long base = (long)row * D + tid * 4;

    float4 xv = *(const float4*)(x + base);
    float4 rv = *(const float4*)(r + base);
    float4 t  = {xv.x + rv.x, xv.y + rv.y, xv.z + rv.z, xv.w + rv.w};

    float s = t.x + t.y + t.z + t.w;
    for (int off = 32; off; off >>= 1) s += __shfl_xor(s, off);
    if ((tid & 63) == 0) red[tid >> 6] = s;
    __syncthreads();
    float mean = (red[0] + red[1] + red[2] + red[3]) * (1.f / (float)D);
    __syncthreads();

    float4 dv = {t.x - mean, t.y - mean, t.z - mean, t.w - mean};
    float sq = dv.x * dv.x + dv.y * dv.y + dv.z * dv.z + dv.w * dv.w;
    for (int off = 32; off; off >>= 1) sq += __shfl_xor(sq, off);
    if ((tid & 63) == 0) red[tid >> 6] = sq;
    __syncthreads();
    float var  = (red[0] + red[1] + red[2] + red[3]) * (1.f / (float)D);
    float rstd = rsqrtf(var + 1e-5f);

    const float* gp = g + (long)grp * paramStride + tid * 4;
    const float* bp = b + (long)grp * paramStride + tid * 4;
    float4 gv = *(const float4*)gp;
    float4 bv = *(const float4*)bp;
    float4 o = {dv.x * rstd * gv.x + bv.x, dv.y * rstd * gv.y + bv.y,
                dv.z * rstd * gv.z + bv.z, dv.w * rstd * gv.w + bv.w};
    *(float4*)(out + base) = o;
}

// ---------------------------------------------------------------------------
__global__ __launch_bounds__(256)
void rowdot_kernel(const float* __restrict__ t, const float* __restrict__ v,
                   float* __restrict__ s)
{
    __shared__ float red[8];
    const int row = blockIdx.x;
    const int tid = threadIdx.x;
    float4 tv = *(const float4*)(t + (long)row * D + tid * 4);
    float4 vv = *(const float4*)(v + tid * 4);
    float p = tv.x * vv.x + tv.y * vv.y + tv.z * vv.z + tv.w * vv.w;
    for (int off = 32; off; off >>= 1) p += __shfl_xor(p, off);
    if ((tid & 63) == 0) red[tid >> 6] = p;
    __syncthreads();
    if (tid == 0) s[row] = red[0] + red[1] + red[2] + red[3];
}

// ---------------------------------------------------------------------------
__global__ void combine_kernel(const float* __restrict__ sb, const float* __restrict__ h,
                               float* __restrict__ out)
{
    long idx = (long)blockIdx.x * 256 + threadIdx.x;   // < LD
    int l = (int)(idx >> 10);
    float s0 = sb[l], s1 = sb[L + l];
    float m  = fmaxf(s0, s1);
    float e0 = expf(s0 - m), e1 = expf(s1 - m);
    float inv = 1.f / (e0 + e1);
    out[idx] = (e0 * h[idx] + e1 * h[LD + idx]) * inv;
}

// ---------------------------------------------------------------------------
__global__ __launch_bounds__(256)
void cls_kernel(const float* __restrict__ x, const float* __restrict__ W,
                const float* __restrict__ b, float* __restrict__ out)
{
    __shared__ float red[4][7];
    __shared__ float logit[7];
    const int row = blockIdx.x;
    const int tid = threadIdx.x;
    float p[7] = {0, 0, 0, 0, 0, 0, 0};
    for (int d = tid; d < D; d += 256) {
        float xv = x[(long)row * D + d];
#pragma unroll
        for (int c = 0; c < 7; ++c) p[c] = fmaf(xv, W[d * 7 + c], p[c]);
    }
#pragma unroll
    for (int c = 0; c < 7; ++c) {
        float v = p[c];
        for (int off = 32; off; off >>= 1) v += __shfl_xor(v, off);
        if ((tid & 63) == 0) red[tid >> 6][c] = v;
    }
    __syncthreads();
    if (tid < 7)
        logit[tid] = red[0][tid] + red[1][tid] + red[2][tid] + red[3][tid] + b[tid];
    __syncthreads();
    if (tid == 0) {
        float mx = logit[0];
        for (int c = 1; c < 7; ++c) mx = fmaxf(mx, logit[c]);
        float sum = 0.f;
        for (int c = 0; c < 7; ++c) sum += expf(logit[c] - mx);
        float lse = logf(sum) + mx;
        for (int c = 0; c < 7; ++c) out[(long)row * 7 + c] = logit[c] - lse;
    }
}

} // anonymous namespace

extern "C" void kernel_launch(void* const* d_in, const int* in_sizes, int n_in,
                              void* d_out, int out_size, void* d_ws, size_t ws_size,
                              hipStream_t stream)
{
    (void)in_sizes; (void)n_in; (void)out_size; (void)ws_size;

    const float* src  = (const float*)d_in[0];
    const int*   utt  = (const int*)d_in[1];
    const int*   spk  = (const int*)d_in[2];
    const int*   winp = (const int*)d_in[3];
    const float* Wqkv = (const float*)d_in[4];
    const float* bqkv = (const float*)d_in[5];
    const float* Wo   = (const float*)d_in[6];
    const float* bo   = (const float*)d_in[7];
    const float* g1   = (const float*)d_in[8];
    const float* b1   = (const float*)d_in[9];
    const float* Wf1  = (const float*)d_in[10];
    const float* bf1  = (const float*)d_in[11];
    const float* Wf2  = (const float*)d_in[12];
    const float* bf2  = (const float*)d_in[13];
    const float* g2   = (const float*)d_in[14];
    const float* b2   = (const float*)d_in[15];
    const float* f1W  = (const float*)d_in[16];
    const float* f1b  = (const float*)d_in[17];
    const float* f1v  = (const float*)d_in[18];
    const float* f2W  = (const float*)d_in[19];
    const float* f2b  = (const float*)d_in[20];
    const float* f2v  = (const float*)d_in[21];
    const float* clsW = (const float*)d_in[22];
    const float* clsb = (const float*)d_in[23];
    float* out = (float*)d_out;

    // ---- workspace arena (floats). ~187 MB total ----
    float* ws    = (float*)d_ws;
    float* x     = ws;               // 3*LD   [3][L][D]
    float* qkv   = x + 3 * LD;       // 9*LD   [3][L][3D]
    float* attno = qkv + 9 * LD;     // 3*LD
    float* tmp   = attno + 3 * LD;   // 3*LD
    float* R1    = tmp + 3 * LD;     // 16*LD shared region
    float* sbuf  = R1 + 16 * LD;     // 2*L
    float* S    = R1;                // [16][L][L] per-branch scores (attention phase)
    float* ffn  = R1;                // [3][L][DFF] (FFN phase)
    float* tbuf = R1;                // [2][L][D]  (fusion phase)
    float* h2   = R1 + 2 * LD;       // [2][L][D]  (fusion phase)
    unsigned short* wpack = (unsigned short*)(sbuf + 2 * L);  // 25.2M shorts (50.3MB)

    add_pe_kernel<<<LD / 256, 256, 0, stream>>>(src, x);

    for (int l = 0; l < NL; ++l) {
        // QKV projection: repack W[l] (3 branches), then packed-B GEMM
        repack_w<<<dim3(6144 / 4, 3), 256, 0, stream>>>(
            Wqkv + (long)l * D * 3 * D, 3 * D, (long)NL * D * 3 * D,
            wpack, (long)2 * D * 3 * D, 3 * D);
        gemm_mfma_pb<128, 128, 0>
            <<<dim3(3 * D / 128, L / 128, 3), 256, 0, stream>>>(
            x, D, LD, wpack, 3 * D, (long)2 * D * 3 * D,
            qkv, 3 * D, 3 * LD, bqkv + (long)l * 3 * D, (long)NL * 3 * D, D, 1.f);

        for (int b = 0; b < 3; ++b) {
            const float* qkvb = qkv + (long)b * 3 * LD;
            // scores: S[h] = q@k^T * 0.125  (NT GEMM, K=64, batched over heads)
            gemm_mfma<128, 128, 0, true>
                <<<dim3(L / 128, L / 128, NH), 256, 0, stream>>>(
                qkvb, 3 * D, 64, qkvb + D, 3 * D, 64,
                S, L, (long)L * L, nullptr, 0, DH, 0.125f);
            softmax_mask_kernel<<<dim3(L, NH), 256, 0, stream>>>(S, utt, spk, winp, b);
            // O[h] = P@V  (M=1024, N=64, K=1024) — BM=64 for 256-block grid
            gemm_mfma<64, 64, 0, false>
                <<<dim3(1, L / 64, NH), 256, 0, stream>>>(
                S, L, (long)L * L, qkvb + 2 * D, 3 * D, 64,
                attno + (long)b * LD, D, 64, nullptr, 0, L, 1.f);
        }

        // output projection
        repack_w<<<dim3(2048 / 4, 3), 256, 0, stream>>>(
            Wo + (long)l * D * D, D, (long)NL * D * D,
            wpack, (long)2 * D * D, D);
        gemm_mfma_pb<128, 128, 0>
            <<<dim3(D / 128, L / 128, 3), 256, 0, stream>>>(
            attno, D, LD, wpack, D, (long)2 * D * D,
            tmp, D, LD, bo + (long)l * D, (long)NL * D, D, 1.f);
        ln_kernel<<<3 * L, 256, 0, stream>>>(x, tmp, g1 + (long)l * D, b1 + (long)l * D,
                                             x, (long)NL * D);
        // FFN
        repack_w<<<dim3(8192 / 4, 3), 256, 0, stream>>>(
            Wf1 + (long)l * D * DFF, DFF, (long)NL * D * DFF,
            wpack, (long)2 * D * DFF, DFF);
        gemm_mfma_pb<128, 128, 1>
            <<<dim3(DFF / 128, L / 128, 3), 256, 0, stream>>>(
            x, D, LD, wpack, DFF, (long)2 * D * DFF,
            ffn, DFF, (long)L * DFF, bf1 + (long)l * DFF, (long)NL * DFF, D, 1.f);
        repack_w<<<dim3(8192 / 4, 3), 256, 0, stream>>>(
            Wf2 + (long)l * DFF * D, D, (long)NL * DFF * D,
            wpack, (long)2 * DFF * D, D);
        gemm_mfma_pb<128, 128, 0>
            <<<dim3(D / 128, L / 128, 3), 256, 0, stream>>>(
            ffn, DFF, (long)L * DFF, wpack, D, (long)2 * DFF * D,
            tmp, D, LD, bf2 + (long)l * D, (long)NL * D, DFF, 1.f);
        ln_kernel<<<3 * L, 256, 0, stream>>>(x, tmp, g2 + (long)l * D, b2 + (long)l * D,
                                             x, (long)NL * D);
    }

    // ---- fusion 1: h = [sm, om] = x[1], x[2] ----
    repack_w<<<dim3(2048 / 4, 1), 256, 0, stream>>>(f1W, D, 0, wpack, 0, D);
    gemm_mfma_pb<128, 128, 2>
        <<<dim3(D / 128, L / 128, 2), 256, 0, stream>>>(
        x + LD, D, LD, wpack, D, 0, tbuf, D, LD, f1b, 0, D, 1.f);
    rowdot_kernel<<<2 * L, 256, 0, stream>>>(tbuf, f1v, sbuf);
    combine_kernel<<<LD / 256, 256, 0, stream>>>(sbuf, x + LD, h2 + LD);   // sp -> h2[1]
    hipMemcpyAsync(h2, x, LD * sizeof(float), hipMemcpyDeviceToDevice, stream); // ct -> h2[0]

    // ---- fusion 2: h = [ct, sp] = h2 ----
    repack_w<<<dim3(2048 / 4, 1), 256, 0, stream>>>(f2W, D, 0, wpack, 0, D);
    gemm_mfma_pb<128, 128, 2>
        <<<dim3(D / 128, L / 128, 2), 256, 0, stream>>>(
        h2, D, LD, wpack, D, 0, tbuf, D, LD, f2b, 0, D, 1.f);
    rowdot_kernel<<<2 * L, 256, 0, stream>>>(tbuf, f2v, sbuf);
    combine_kernel<<<LD / 256, 256, 0, stream>>>(sbuf, h2, tmp);           // fused -> tmp

    // ---- classifier + log_softmax ----
    cls_kernel<<<L, 256, 0, stream>>>(tmp, clsW, clsb, out);
}

// Round 4
// 2604.742 us; speedup vs baseline: 1.0388x; 1.0388x over previous
//
#include <hip/hip_runtime.h>
#include <cmath>

namespace {

constexpr int L   = 1024;
constexpr int D   = 1024;
constexpr int DFF = 4096;
constexpr int NL  = 3;
constexpr int NH  = 16;
constexpr int DH  = 64;
constexpr long LD = (long)L * D;   // 1048576

typedef __attribute__((ext_vector_type(8))) short bf16x8;  // 8 bf16 (4 VGPRs)
typedef __attribute__((ext_vector_type(4))) float f32x4;   // MFMA C/D

// Split fp32 into hi/lo bf16 (truncation split)
__device__ inline void split1(float f, unsigned short& h, unsigned short& l)
{
    unsigned u = __float_as_uint(f);
    h = (unsigned short)(u >> 16);
    float hf = __uint_as_float(u & 0xffff0000u);
    l = (unsigned short)(__float_as_uint(f - hf) >> 16);
}

// Bijective XCD-chunk swizzle of the flat block index (requires nwg % 8 == 0).
// Returns decoded (bx, by, bz) with x fastest so one XCD owns contiguous tiles.
__device__ inline void xcd_decode(int& bx, int& by, int& bz)
{
    const int gx = gridDim.x, gy = gridDim.y;
    const int nwg = gx * gy * gridDim.z;
    int flat = blockIdx.x + gx * (blockIdx.y + gy * blockIdx.z);
    int w = (flat & 7) * (nwg >> 3) + (flat >> 3);
    bz = w / (gx * gy);
    int rem = w - bz * gx * gy;
    by = rem / gx;
    bx = rem - by * gx;
}

// ---------------------------------------------------------------------------
// Weight repack: fp32 [K x N] -> fragment-ordered hi/lo bf16 (2KB chunks).
// ---------------------------------------------------------------------------
__global__ __launch_bounds__(256)
void repack_w(const float* __restrict__ W, int ldw, long sW,
              unsigned short* __restrict__ out, long sOut, int Np)
{
    const int t    = threadIdx.x;
    const int lane = t & 63;
    const int c    = blockIdx.x * 4 + (t >> 6);
    const int z    = blockIdx.y;
    const int nch  = Np >> 4;
    const int k0   = (c / nch) * 32 + ((lane >> 4) << 3);
    const int n    = (c % nch) * 16 + (lane & 15);
    const float* Wz = W + (long)z * sW + n;
    unsigned short* oz = out + (long)z * sOut + (long)c * 1024 + (lane << 3);
    unsigned short h[8], l[8];
#pragma unroll
    for (int e = 0; e < 8; ++e)
        split1(Wz[(long)(k0 + e) * ldw], h[e], l[e]);
    *(ushort4*)(oz)       = *(ushort4*)&h[0];
    *(ushort4*)(oz + 4)   = *(ushort4*)&h[4];
    *(ushort4*)(oz + 512) = *(ushort4*)&l[0];
    *(ushort4*)(oz + 516) = *(ushort4*)&l[4];
}

// ---------------------------------------------------------------------------
// Pipelined packed-B MFMA GEMM with split-K support.
//  C_slice[ks] = (ks==0 ? bias : 0) + alpha * A @ B[k0:k1]
//  - A fp32 [M x K], staged hi/lo bf16 through double-buffered LDS
//  - B pre-packed fragment-order (repack_w), global->regs, no LDS
//  - ONE raw barrier per K-step, lgkmcnt-only drain; global loads (to regs)
//    stay in flight across barriers (counted vmcnt by compiler).
//  blockIdx.z encodes batch*ksl + kslice. ACT must be 0 when ksl > 1.
// ---------------------------------------------------------------------------
template<int BM, int BN, int ACT>
__global__ __launch_bounds__(256)
void gemm_mfma_pb(const float* __restrict__ A, int lda, long sA,
                  const unsigned short* __restrict__ Bp, int Np, long sBp,
                  float* __restrict__ C, int ldc, long sC,
                  const float* __restrict__ bias, long sBias,
                  int K, float alpha, int ksl, long sSlice)
{
    constexpr int BK = 32;
    constexpr int PK = 40;              // 80B row stride (16B-aligned, period-8 banks)
    constexpr int FM = BM / 32;
    constexpr int FN = BN / 32;
    constexpr int NA = BM / 32;

    __shared__ __align__(16) unsigned short Ah0[BM][PK], Al0[BM][PK];
    __shared__ __align__(16) unsigned short Ah1[BM][PK], Al1[BM][PK];

    int bx, by, bz;
    xcd_decode(bx, by, bz);
    const int zb = bz / ksl, ks = bz - zb * ksl;
    const int kLen = K / ksl, k0 = ks * kLen;
    const int nit = kLen / BK;          // even (>= 8) at every call site

    const int tid  = threadIdx.x;
    const int lane = tid & 63;
    const int wave = tid >> 6;
    const int wm   = (wave >> 1) * (BM / 2);
    const int wn   = (wave & 1)  * (BN / 2);
    const int lr   = lane & 15;
    const int ko   = (lane >> 4) * 8;

    const float* Abase = A + (long)zb * sA;
    const unsigned short* Bb = Bp + (long)zb * sBp;
    float* Cbase = C + (long)zb * sC + (long)ks * sSlice;
    const int n0  = bx * BN;
    const int m0  = by * BM;
    const int nch = Np >> 4;
    const int cb  = (n0 + wn) >> 4;

    f32x4 acc[FM][FN];
#pragma unroll
    for (int i = 0; i < FM; ++i)
#pragma unroll
        for (int j = 0; j < FN; ++j) acc[i][j] = f32x4{0.f, 0.f, 0.f, 0.f};

    const int akq = tid & 7;
    const int amr = tid >> 3;

    auto loadA = [&](int kt, float4* pa) {
#pragma unroll
        for (int r = 0; r < NA; ++r)
            pa[r] = *(const float4*)(Abase + (long)(m0 + r * 32 + amr) * lda + kt + akq * 4);
    };
    auto storeA = [&](unsigned short (*AhD)[PK], unsigned short (*AlD)[PK],
                      const float4* pa) {
#pragma unroll
        for (int r = 0; r < NA; ++r) {
            ushort4 h, l;
            split1(pa[r].x, h.x, l.x); split1(pa[r].y, h.y, l.y);
            split1(pa[r].z, h.z, l.z); split1(pa[r].w, h.w, l.w);
            *(ushort4*)&AhD[r * 32 + amr][akq * 4] = h;
            *(ushort4*)&AlD[r * 32 + amr][akq * 4] = l;
        }
    };
    auto loadB = [&](int kt, bf16x8* h, bf16x8* l) {
        const unsigned short* p = Bb + ((long)(kt >> 5) * nch + cb) * 1024 + (lane << 3);
#pragma unroll
        for (int ni = 0; ni < FN; ++ni) {
            h[ni] = *(const bf16x8*)(p + ni * 1024);
            l[ni] = *(const bf16x8*)(p + ni * 1024 + 512);
        }
    };
    auto mmaStep = [&](unsigned short (*AhS)[PK], unsigned short (*AlS)[PK],
                       const bf16x8* bh, const bf16x8* bl) {
        bf16x8 ah[FM], al[FM];
#pragma unroll
        for (int mi = 0; mi < FM; ++mi) {
            ah[mi] = *(const bf16x8*)&AhS[wm + mi * 16 + lr][ko];
            al[mi] = *(const bf16x8*)&AlS[wm + mi * 16 + lr][ko];
        }
#pragma unroll
        for (int mi = 0; mi < FM; ++mi)
#pragma unroll
            for (int ni = 0; ni < FN; ++ni) {
                acc[mi][ni] = __builtin_amdgcn_mfma_f32_16x16x32_bf16(
                    ah[mi], bh[ni], acc[mi][ni], 0, 0, 0);
                acc[mi][ni] = __builtin_amdgcn_mfma_f32_16x16x32_bf16(
                    ah[mi], bl[ni], acc[mi][ni], 0, 0, 0);
                acc[mi][ni] = __builtin_amdgcn_mfma_f32_16x16x32_bf16(
                    al[mi], bh[ni], acc[mi][ni], 0, 0, 0);
            }
    };
    auto bar = [&]() {
        asm volatile("s_waitcnt lgkmcnt(0)" ::: "memory");
        __builtin_amdgcn_s_barrier();
    };

    float4 paA[NA], paB[NA];
    bf16x8 bhE[FN], blE[FN], bhO[FN], blO[FN];

    // prologue: tile0 -> buf0; tile1 A in regs; B tile0/tile1 in regs
    loadA(k0, paA);
    loadB(k0, bhE, blE);
    loadA(k0 + BK, paB);
    storeA(Ah0, Al0, paA);          // waits only on paA loads (counted vmcnt)
    loadB(k0 + BK, bhO, blO);
    bar();

    for (int t = 0; t < nit; t += 2) {
        // ---- phase A: compute tile t from buf0 ----
        if (t + 2 < nit) loadA(k0 + (t + 2) * BK, paA);
        mmaStep(Ah0, Al0, bhE, blE);
        if (t + 2 < nit) loadB(k0 + (t + 2) * BK, bhE, blE);
        storeA(Ah1, Al1, paB);      // tile t+1 -> buf1
        bar();
        // ---- phase B: compute tile t+1 from buf1 ----
        if (t + 3 < nit) loadA(k0 + (t + 3) * BK, paB);
        mmaStep(Ah1, Al1, bhO, blO);
        if (t + 3 < nit) loadB(k0 + (t + 3) * BK, bhO, blO);
        if (t + 2 < nit) {
            storeA(Ah0, Al0, paA);  // tile t+2 -> buf0
            bar();
        }
    }

    // ---- epilogue: C/D layout col = lane&15, row = (lane>>4)*4 + reg ----
    float bv[FN];
#pragma unroll
    for (int ni = 0; ni < FN; ++ni)
        bv[ni] = (bias && ks == 0)
               ? bias[(long)zb * sBias + n0 + wn + ni * 16 + lr] : 0.f;
    const int cr = (lane >> 4) * 4;
#pragma unroll
    for (int mi = 0; mi < FM; ++mi)
#pragma unroll
        for (int ni = 0; ni < FN; ++ni) {
#pragma unroll
            for (int r = 0; r < 4; ++r) {
                float t = acc[mi][ni][r] * alpha + bv[ni];
                if (ACT == 1) t = fmaxf(t, 0.f);
                else if (ACT == 2) t = tanhf(t);
                Cbase[(long)(m0 + wm + mi * 16 + cr + r) * ldc
                      + n0 + wn + ni * 16 + lr] = t;
            }
        }
}

// ---------------------------------------------------------------------------
// Dynamic-B split-bf16 MFMA GEMM (QK^T and PV; both use BT=true now).
// ---------------------------------------------------------------------------
template<int BM, int BN, int ACT, bool BT>
__global__ __launch_bounds__(256)
void gemm_mfma(const float* __restrict__ A, int lda, long sA,
               const float* __restrict__ B, int ldb, long sB,
               float* __restrict__ C, int ldc, long sC,
               const float* __restrict__ bias, long sBias,
               int K, float alpha)
{
    constexpr int BK = 32;
    constexpr int PK = 40;
    constexpr int FM = BM / 32;
    constexpr int FN = BN / 32;
    constexpr int NA = BM / 32;
    constexpr int NB = BN / 32;   // BT=true staging mirrors A

    __shared__ __align__(16) unsigned short Ah[BM][PK], Al[BM][PK];
    __shared__ __align__(16) unsigned short Bh[BN][PK], Bl[BN][PK];

    int bx, by, bz;
    xcd_decode(bx, by, bz);

    const int tid  = threadIdx.x;
    const int lane = tid & 63;
    const int wave = tid >> 6;
    const int wm   = (wave >> 1) * (BM / 2);
    const int wn   = (wave & 1)  * (BN / 2);
    const int lr   = lane & 15;
    const int ko   = (lane >> 4) * 8;

    const float* Abase = A + (long)bz * sA;
    const float* Bbase = B + (long)bz * sB;
    float*       Cbase = C + (long)bz * sC;
    const int n0 = bx * BN;
    const int m0 = by * BM;

    f32x4 acc[FM][FN];
#pragma unroll
    for (int i = 0; i < FM; ++i)
#pragma unroll
        for (int j = 0; j < FN; ++j) acc[i][j] = f32x4{0.f, 0.f, 0.f, 0.f};

    const int akq = tid & 7;
    const int amr = tid >> 3;

    auto loadA = [&](int kt, float4* pa) {
#pragma unroll
        for (int r = 0; r < NA; ++r)
            pa[r] = *(const float4*)(Abase + (long)(m0 + r * 32 + amr) * lda + kt + akq * 4);
    };
    auto loadB = [&](int kt, float4* pb) {
#pragma unroll
        for (int r = 0; r < NB; ++r)
            pb[r] = *(const float4*)(Bbase + (long)(n0 + r * 32 + amr) * ldb + kt + akq * 4);
    };
    auto storeA = [&](const float4* pa) {
#pragma unroll
        for (int r = 0; r < NA; ++r) {
            ushort4 h, l;
            split1(pa[r].x, h.x, l.x); split1(pa[r].y, h.y, l.y);
            split1(pa[r].z, h.z, l.z); split1(pa[r].w, h.w, l.w);
            *(ushort4*)&Ah[r * 32 + amr][akq * 4] = h;
            *(ushort4*)&Al[r * 32 + amr][akq * 4] = l;
        }
    };
    auto storeB = [&](const float4* pb) {
#pragma unroll
        for (int r = 0; r < NB; ++r) {
            ushort4 h, l;
            split1(pb[r].x, h.x, l.x); split1(pb[r].y, h.y, l.y);
            split1(pb[r].z, h.z, l.z); split1(pb[r].w, h.w, l.w);
            *(ushort4*)&Bh[r * 32 + amr][akq * 4] = h;
            *(ushort4*)&Bl[r * 32 + amr][akq * 4] = l;
        }
    };

    float4 pa[NA], pb[NB];
    loadA(0, pa); loadB(0, pb);

    for (int kt = 0; kt < K; kt += BK) {
        storeA(pa);
        storeB(pb);
        __syncthreads();

        const bool more = kt + BK < K;
        float4 na[NA], nb[NB];
        if (more) { loadA(kt + BK, na); loadB(kt + BK, nb); }

        bf16x8 ah[FM], al[FM], bh[FN], bl[FN];
#pragma unroll
        for (int mi = 0; mi < FM; ++mi) {
            ah[mi] = *(const bf16x8*)&Ah[wm + mi * 16 + lr][ko];
            al[mi] = *(const bf16x8*)&Al[wm + mi * 16 + lr][ko];
        }
#pragma unroll
        for (int ni = 0; ni < FN; ++ni) {
            bh[ni] = *(const bf16x8*)&Bh[wn + ni * 16 + lr][ko];
            bl[ni] = *(const bf16x8*)&Bl[wn + ni * 16 + lr][ko];
        }
#pragma unroll
        for (int mi = 0; mi < FM; ++mi)
#pragma unroll
            for (int ni = 0; ni < FN; ++ni) {
                acc[mi][ni] = __builtin_amdgcn_mfma_f32_16x16x32_bf16(
                    ah[mi], bh[ni], acc[mi][ni], 0, 0, 0);
                acc[mi][ni] = __builtin_amdgcn_mfma_f32_16x16x32_bf16(
                    ah[mi], bl[ni], acc[mi][ni], 0, 0, 0);
                acc[mi][ni] = __builtin_amdgcn_mfma_f32_16x16x32_bf16(
                    al[mi], bh[ni], acc[mi][ni], 0, 0, 0);
            }
        __syncthreads();

        if (more) {
#pragma unroll
            for (int r = 0; r < NA; ++r) pa[r] = na[r];
#pragma unroll
            for (int r = 0; r < NB; ++r) pb[r] = nb[r];
        }
    }

    float bv[FN];
#pragma unroll
    for (int ni = 0; ni < FN; ++ni)
        bv[ni] = bias ? bias[(long)bz * sBias + n0 + wn + ni * 16 + lr] : 0.f;
    const int cr = (lane >> 4) * 4;
#pragma unroll
    for (int mi = 0; mi < FM; ++mi)
#pragma unroll
        for (int ni = 0; ni < FN; ++ni) {
#pragma unroll
            for (int r = 0; r < 4; ++r) {
                float t = acc[mi][ni][r] * alpha + bv[ni];
                if (ACT == 1) t = fmaxf(t, 0.f);
                else if (ACT == 2) t = tanhf(t);
                Cbase[(long)(m0 + wm + mi * 16 + cr + r) * ldc
                      + n0 + wn + ni * 16 + lr] = t;
            }
        }
}

// ---------------------------------------------------------------------------
// vt[b][c][l] = qkv[b][l][2048 + c]  (V transposed per branch, c = h*64+dh)
// ---------------------------------------------------------------------------
__global__ __launch_bounds__(256)
void vtrans_kernel(const float* __restrict__ qkv, float* __restrict__ vt)
{
    __shared__ float t[32][33];
    const int b  = blockIdx.z;
    const int l0 = blockIdx.x * 32, c0 = blockIdx.y * 32;
    const int tx = threadIdx.x & 31, ty = threadIdx.x >> 5;
    const float* src = qkv + (long)b * 3 * LD + 2048;
#pragma unroll
    for (int r = ty; r < 32; r += 8)
        t[r][tx] = src[(long)(l0 + r) * 3072 + c0 + tx];
    __syncthreads();
    float* dst = vt + (long)b * LD;
#pragma unroll
    for (int r = ty; r < 32; r += 8)
        dst[(long)(c0 + r) * L + l0 + tx] = t[tx][r];
}

// ---------------------------------------------------------------------------
__global__ void add_pe_kernel(const float* __restrict__ src, float* __restrict__ x)
{
    long idx = (long)blockIdx.x * 256 + threadIdx.x;   // < LD
    int pos = (int)(idx >> 10);
    int d   = (int)(idx & 1023);
    float expnt = (float)(d & ~1) * (1.0f / (float)D);
    float denom = powf(10000.0f, expnt);
    float ang   = (float)pos / denom;
    float pe    = (d & 1) ? cosf(ang) : sinf(ang);
    float v = src[idx] + pe;
    x[idx]          = v;
    x[LD + idx]     = v;
    x[2 * LD + idx] = v;
}

// ---------------------------------------------------------------------------
__global__ __launch_bounds__(256)
void softmax_mask_kernel(float* __restrict__ S, const int* __restrict__ utt,
                         const int* __restrict__ spk, const int* __restrict__ winp,
                         int branch)
{
    __shared__ float red[8];
    const int i   = blockIdx.x;
    const int h   = blockIdx.y;
    const int tid = threadIdx.x;
    float* row = S + ((long)h * L + i) * L;
    const int window = winp[0];
    const int utti   = utt[i];
    const int spki   = spk[i];
    const int j0 = tid * 4;

    float4 sv = *(float4*)(row + j0);
    float s[4] = {sv.x, sv.y, sv.z, sv.w};
#pragma unroll
    for (int c = 0; c < 4; ++c) {
        int j = j0 + c;
        int dd = j - i;
        bool win  = (dd <= window) && (-dd <= window);
        bool base = win && (utti > 0) && (utt[j] > 0);
        bool same = (spk[j] == spki);
        bool keep = (branch == 0) ? base
                  : (branch == 1) ? (base && same)
                  : (base && (!same || (j == i)));
        s[c] += keep ? 0.f : -1e9f;
    }
    float mx = fmaxf(fmaxf(s[0], s[1]), fmaxf(s[2], s[3]));
    for (int off = 32; off; off >>= 1) mx = fmaxf(mx, __shfl_xor(mx, off));
    if ((tid & 63) == 0) red[tid >> 6] = mx;
    __syncthreads();
    mx = fmaxf(fmaxf(red[0], red[1]), fmaxf(red[2], red[3]));
    __syncthreads();

    float e[4]; float sum = 0.f;
#pragma unroll
    for (int c = 0; c < 4; ++c) { e[c] = expf(s[c] - mx); sum += e[c]; }
    for (int off = 32; off; off >>= 1) sum += __shfl_xor(sum, off);
    if ((tid & 63) == 0) red[tid >> 6] = sum;
    __syncthreads();
    float inv = 1.f / (red[0] + red[1] + red[2] + red[3]);

    float4 o = {e[0] * inv, e[1] * inv, e[2] * inv, e[3] * inv};
    *(float4*)(row + j0) = o;
}

// ---------------------------------------------------------------------------
// LayerNorm: out = LN(x + sum_{s<nslc} r[s]) * g + b (r slices stride sSlice)
// ---------------------------------------------------------------------------
__global__ __launch_bounds__(256)
void ln_kernel(const float* __restrict__ x, const float* __restrict__ r,
               int nslc, long sSlice,
               const float* __restrict__ g, const float* __restrict__ b,
               float* __restrict__ out, long paramStride)
{
    __shared__ float red[8];
    const int row = blockIdx.x;
    const int grp = row >> 10;
    const int tid = threadIdx.x;
    const long base = (long)row * D + tid * 4;

    float4 t = *(const float4*)(x + base);
    for (int s = 0; s < nslc; ++s) {
        float4 rv = *(const float4*)(r + (long)s * sSlice + base);
        t.x += rv.x; t.y += rv.y; t.z += rv.z; t.w += rv.w;
    }

    float sm = t.x + t.y + t.z + t.w;
    for (int off = 32; off; off >>= 1) sm += __shfl_xor(sm, off);
    if ((tid & 63) == 0) red[tid >> 6] = sm;
    __syncthreads();
    float mean = (red[0] + red[1] + red[2] + red[3]) * (1.f / (float)D);
    __syncthreads();

    float4 dv = {t.x - mean, t.y - mean, t.z - mean, t.w - mean};
    float sq = dv.x * dv.x + dv.y * dv.y + dv.z * dv.z + dv.w * dv.w;
    for (int off = 32; off; off >>= 1) sq += __shfl_xor(sq, off);
    if ((tid & 63) == 0) red[tid >> 6] = sq;
    __syncthreads();
    float var  = (red[0] + red[1] + red[2] + red[3]) * (1.f / (float)D);
    float rstd = rsqrtf(var + 1e-5f);

    const float* gp = g + (long)grp * paramStride + tid * 4;
    const float* bp = b + (long)grp * paramStride + tid * 4;
    float4 gv = *(const float4*)gp;
    float4 bv = *(const float4*)bp;
    float4 o = {dv.x * rstd * gv.x + bv.x, dv.y * rstd * gv.y + bv.y,
                dv.z * rstd * gv.z + bv.z, dv.w * rstd * gv.w + bv.w};
    *(float4*)(out + base) = o;
}

// ---------------------------------------------------------------------------
// s[row] = dot(tanh(sum_slices t[row]), v); rows = 2*L
// ---------------------------------------------------------------------------
__global__ __launch_bounds__(256)
void rowdot_kernel(const float* __restrict__ t, long sSlice, int nslc,
                   const float* __restrict__ v, float* __restrict__ s)
{
    __shared__ float red[8];
    const int row = blockIdx.x;
    const int tid = threadIdx.x;
    const long base = (long)row * D + tid * 4;
    float4 a = *(const float4*)(t + base);
    for (int sl = 1; sl < nslc; ++sl) {
        float4 a2 = *(const float4*)(t + (long)sl * sSlice + base);
        a.x += a2.x; a.y += a2.y; a.z += a2.z; a.w += a2.w;
    }
    a.x = tanhf(a.x); a.y = tanhf(a.y); a.z = tanhf(a.z); a.w = tanhf(a.w);
    float4 vv = *(const float4*)(v + tid * 4);
    float p = a.x * vv.x + a.y * vv.y + a.z * vv.z + a.w * vv.w;
    for (int off = 32; off; off >>= 1) p += __shfl_xor(p, off);
    if ((tid & 63) == 0) red[tid >> 6] = p;
    __syncthreads();
    if (tid == 0) s[row] = red[0] + red[1] + red[2] + red[3];
}

// ---------------------------------------------------------------------------
__global__ void combine_kernel(const float* __restrict__ sb, const float* __restrict__ h,
                               float* __restrict__ out)
{
    long idx = (long)blockIdx.x * 256 + threadIdx.x;   // < LD
    int l = (int)(idx >> 10);
    float s0 = sb[l], s1 = sb[L + l];
    float m  = fmaxf(s0, s1);
    float e0 = expf(s0 - m), e1 = expf(s1 - m);
    float inv = 1.f / (e0 + e1);
    out[idx] = (e0 * h[idx] + e1 * h[LD + idx]) * inv;
}

// ---------------------------------------------------------------------------
__global__ __launch_bounds__(256)
void cls_kernel(const float* __restrict__ x, const float* __restrict__ W,
                const float* __restrict__ b, float* __restrict__ out)
{
    __shared__ float red[4][7];
    __shared__ float logit[7];
    const int row = blockIdx.x;
    const int tid = threadIdx.x;
    float p[7] = {0, 0, 0, 0, 0, 0, 0};
    for (int d = tid; d < D; d += 256) {
        float xv = x[(long)row * D + d];
#pragma unroll
        for (int c = 0; c < 7; ++c) p[c] = fmaf(xv, W[d * 7 + c], p[c]);
    }
#pragma unroll
    for (int c = 0; c < 7; ++c) {
        float v = p[c];
        for (int off = 32; off; off >>= 1) v += __shfl_xor(v, off);
        if ((tid & 63) == 0) red[tid >> 6][c] = v;
    }
    __syncthreads();
    if (tid < 7)
        logit[tid] = red[0][tid] + red[1][tid] + red[2][tid] + red[3][tid] + b[tid];
    __syncthreads();
    if (tid == 0) {
        float mx = logit[0];
        for (int c = 1; c < 7; ++c) mx = fmaxf(mx, logit[c]);
        float sum = 0.f;
        for (int c = 0; c < 7; ++c) sum += expf(logit[c] - mx);
        float lse = logf(sum) + mx;
        for (int c = 0; c < 7; ++c) out[(long)row * 7 + c] = logit[c] - lse;
    }
}

} // anonymous namespace

extern "C" void kernel_launch(void* const* d_in, const int* in_sizes, int n_in,
                              void* d_out, int out_size, void* d_ws, size_t ws_size,
                              hipStream_t stream)
{
    (void)in_sizes; (void)n_in; (void)out_size; (void)ws_size;

    const float* src  = (const float*)d_in[0];
    const int*   utt  = (const int*)d_in[1];
    const int*   spk  = (const int*)d_in[2];
    const int*   winp = (const int*)d_in[3];
    const float* Wqkv = (const float*)d_in[4];
    const float* bqkv = (const float*)d_in[5];
    const float* Wo   = (const float*)d_in[6];
    const float* bo   = (const float*)d_in[7];
    const float* g1   = (const float*)d_in[8];
    const float* b1   = (const float*)d_in[9];
    const float* Wf1  = (const float*)d_in[10];
    const float* bf1  = (const float*)d_in[11];
    const float* Wf2  = (const float*)d_in[12];
    const float* bf2  = (const float*)d_in[13];
    const float* g2   = (const float*)d_in[14];
    const float* b2   = (const float*)d_in[15];
    const float* f1W  = (const float*)d_in[16];
    const float* f1b  = (const float*)d_in[17];
    const float* f1v  = (const float*)d_in[18];
    const float* f2W  = (const float*)d_in[19];
    const float* f2b  = (const float*)d_in[20];
    const float* f2v  = (const float*)d_in[21];
    const float* clsW = (const float*)d_in[22];
    const float* clsb = (const float*)d_in[23];
    float* out = (float*)d_out;

    // ---- workspace arena (floats) — same footprint as round 3 (~190 MB) ----
    float* ws    = (float*)d_ws;
    float* x     = ws;               // 3*LD   [3][L][D]
    float* qkv   = x + 3 * LD;       // 9*LD   [3][L][3D]; later FFN2 slice scratch
    float* attno = qkv + 9 * LD;     // 3*LD   ; tail of FFN2 slice scratch
    float* tmp   = attno + 3 * LD;   // 3*LD   ; vt during attention; fusion out
    float* R1    = tmp + 3 * LD;     // 16*LD  S / Wo-slices / ffn / fusion slices
    float* sbuf  = R1 + 16 * LD;     // 2*L
    float* S    = R1;                // [16][L][L] scores (attention phase)
    float* ffn  = R1;                // [3][L][DFF] (FFN phase)
    float* vt   = tmp;               // [3][D][L] transposed V (attention phase)
    float* f2s  = qkv;               // [4][3][L][D] FFN2 slices (spans qkv+attno)
    float* h2   = R1 + 4 * LD;       // [2][L][D] (fusion phase)
    unsigned short* wpack = (unsigned short*)(sbuf + 2 * L);  // 25.2M shorts

    add_pe_kernel<<<LD / 256, 256, 0, stream>>>(src, x);

    for (int l = 0; l < NL; ++l) {
        // QKV projection (no split-K; grid 576)
        repack_w<<<dim3(6144 / 4, 3), 256, 0, stream>>>(
            Wqkv + (long)l * D * 3 * D, 3 * D, (long)NL * D * 3 * D,
            wpack, (long)2 * D * 3 * D, 3 * D);
        gemm_mfma_pb<128, 128, 0>
            <<<dim3(3 * D / 128, L / 128, 3), 256, 0, stream>>>(
            x, D, LD, wpack, 3 * D, (long)2 * D * 3 * D,
            qkv, 3 * D, 3 * LD, bqkv + (long)l * 3 * D, (long)NL * 3 * D,
            D, 1.f, 1, 0);

        // transpose V for all branches: vt[b][c][l]
        vtrans_kernel<<<dim3(L / 32, D / 32, 3), 256, 0, stream>>>(qkv, vt);

        for (int b = 0; b < 3; ++b) {
            const float* qkvb = qkv + (long)b * 3 * LD;
            // scores: S[h] = q@k^T * 0.125
            gemm_mfma<128, 128, 0, true>
                <<<dim3(L / 128, L / 128, NH), 256, 0, stream>>>(
                qkvb, 3 * D, 64, qkvb + D, 3 * D, 64,
                S, L, (long)L * L, nullptr, 0, DH, 0.125f);
            softmax_mask_kernel<<<dim3(L, NH), 256, 0, stream>>>(S, utt, spk, winp, b);
            // O[h] = P @ V  via V^T rows (BT=true), BM=64 -> 256 blocks
            gemm_mfma<64, 64, 0, true>
                <<<dim3(1, L / 64, NH), 256, 0, stream>>>(
                S, L, (long)L * L, vt + (long)b * LD, L, (long)64 * L,
                attno + (long)b * LD, D, 64, nullptr, 0, L, 1.f);
        }

        // output projection, split-K=4 -> slices in R1, summed in ln
        repack_w<<<dim3(2048 / 4, 3), 256, 0, stream>>>(
            Wo + (long)l * D * D, D, (long)NL * D * D,
            wpack, (long)2 * D * D, D);
        gemm_mfma_pb<128, 128, 0>
            <<<dim3(D / 128, L / 128, 12), 256, 0, stream>>>(
            attno, D, LD, wpack, D, (long)2 * D * D,
            R1, D, LD, bo + (long)l * D, (long)NL * D,
            D, 1.f, 4, (long)3 * LD);
        ln_kernel<<<3 * L, 256, 0, stream>>>(x, R1, 4, (long)3 * LD,
                                             g1 + (long)l * D, b1 + (long)l * D,
                                             x, (long)NL * D);
        // FFN1 (relu, no split-K; grid 768)
        repack_w<<<dim3(8192 / 4, 3), 256, 0, stream>>>(
            Wf1 + (long)l * D * DFF, DFF, (long)NL * D * DFF,
            wpack, (long)2 * D * DFF, DFF);
        gemm_mfma_pb<128, 128, 1>
            <<<dim3(DFF / 128, L / 128, 3), 256, 0, stream>>>(
            x, D, LD, wpack, DFF, (long)2 * D * DFF,
            ffn, DFF, (long)L * DFF, bf1 + (long)l * DFF, (long)NL * DFF,
            D, 1.f, 1, 0);
        // FFN2, split-K=4 -> slices in f2s, summed in ln
        repack_w<<<dim3(8192 / 4, 3), 256, 0, stream>>>(
            Wf2 + (long)l * DFF * D, D, (long)NL * DFF * D,
            wpack, (long)2 * DFF * D, D);
        gemm_mfma_pb<128, 128, 0>
            <<<dim3(D / 128, L / 128, 12), 256, 0, stream>>>(
            ffn, DFF, (long)L * DFF, wpack, D, (long)2 * DFF * D,
            f2s, D, LD, bf2 + (long)l * D, (long)NL * D,
            DFF, 1.f, 4, (long)3 * LD);
        ln_kernel<<<3 * L, 256, 0, stream>>>(x, f2s, 4, (long)3 * LD,
                                             g2 + (long)l * D, b2 + (long)l * D,
                                             x, (long)NL * D);
    }

    // ---- fusion 1: h = [sm, om] = x[1], x[2]; split-K=2, tanh in rowdot ----
    repack_w<<<dim3(2048 / 4, 1), 256, 0, stream>>>(f1W, D, 0, wpack, 0, D);
    gemm_mfma_pb<128, 128, 0>
        <<<dim3(D / 128, L / 128, 4), 256, 0, stream>>>(
        x + LD, D, LD, wpack, D, 0, R1, D, LD, f1b, 0, D, 1.f, 2, (long)2 * LD);
    rowdot_kernel<<<2 * L, 256, 0, stream>>>(R1, (long)2 * LD, 2, f1v, sbuf);
    combine_kernel<<<LD / 256, 256, 0, stream>>>(sbuf, x + LD, h2 + LD);   // sp -> h2[1]
    hipMemcpyAsync(h2, x, LD * sizeof(float), hipMemcpyDeviceToDevice, stream); // ct

    // ---- fusion 2: h = [ct, sp] = h2 ----
    repack_w<<<dim3(2048 / 4, 1), 256, 0, stream>>>(f2W, D, 0, wpack, 0, D);
    gemm_mfma_pb<128, 128, 0>
        <<<dim3(D / 128, L / 128, 4), 256, 0, stream>>>(
        h2, D, LD, wpack, D, 0, R1, D, LD, f2b, 0, D, 1.f, 2, (long)2 * LD);
    rowdot_kernel<<<2 * L, 256, 0, stream>>>(R1, (long)2 * LD, 2, f2v, sbuf);
    combine_kernel<<<LD / 256, 256, 0, stream>>>(sbuf, h2, tmp);           // fused -> tmp

    // ---- classifier + log_softmax ----
    cls_kernel<<<L, 256, 0, stream>>>(tmp, clsW, clsb, out);
}

// Round 5
// 2270.283 us; speedup vs baseline: 1.1919x; 1.1473x over previous
//
#include <hip/hip_runtime.h>
#include <cmath>

namespace {

constexpr int L   = 1024;
constexpr int D   = 1024;
constexpr int DFF = 4096;
constexpr int NL  = 3;
constexpr int NH  = 16;
constexpr int DH  = 64;
constexpr long LD = (long)L * D;   // 1048576

typedef __attribute__((ext_vector_type(8))) short bf16x8;  // 8 bf16 (4 VGPRs)
typedef __attribute__((ext_vector_type(4))) float f32x4;   // MFMA C/D

// Split fp32 into hi/lo bf16 (truncation split)
__device__ inline void split1(float f, unsigned short& h, unsigned short& l)
{
    unsigned u = __float_as_uint(f);
    h = (unsigned short)(u >> 16);
    float hf = __uint_as_float(u & 0xffff0000u);
    l = (unsigned short)(__float_as_uint(f - hf) >> 16);
}

// Bijective XCD-chunk swizzle of the flat block index (requires nwg % 8 == 0).
__device__ inline void xcd_decode(int& bx, int& by, int& bz)
{
    const int gx = gridDim.x, gy = gridDim.y;
    const int nwg = gx * gy * gridDim.z;
    int flat = blockIdx.x + gx * (blockIdx.y + gy * blockIdx.z);
    int w = (flat & 7) * (nwg >> 3) + (flat >> 3);
    bz = w / (gx * gy);
    int rem = w - bz * gx * gy;
    by = rem / gx;
    bx = rem - by * gx;
}

// ---------------------------------------------------------------------------
// Weight repack: fp32 [K x N] -> fragment-ordered hi/lo bf16 (2KB chunks).
// ---------------------------------------------------------------------------
__global__ __launch_bounds__(256)
void repack_w(const float* __restrict__ W, int ldw, long sW,
              unsigned short* __restrict__ out, long sOut, int Np)
{
    const int t    = threadIdx.x;
    const int lane = t & 63;
    const int c    = blockIdx.x * 4 + (t >> 6);
    const int z    = blockIdx.y;
    const int nch  = Np >> 4;
    const int k0   = (c / nch) * 32 + ((lane >> 4) << 3);
    const int n    = (c % nch) * 16 + (lane & 15);
    const float* Wz = W + (long)z * sW + n;
    unsigned short* oz = out + (long)z * sOut + (long)c * 1024 + (lane << 3);
    unsigned short h[8], l[8];
#pragma unroll
    for (int e = 0; e < 8; ++e)
        split1(Wz[(long)(k0 + e) * ldw], h[e], l[e]);
    *(ushort4*)(oz)       = *(ushort4*)&h[0];
    *(ushort4*)(oz + 4)   = *(ushort4*)&h[4];
    *(ushort4*)(oz + 512) = *(ushort4*)&l[0];
    *(ushort4*)(oz + 516) = *(ushort4*)&l[4];
}

// ---------------------------------------------------------------------------
// Pipelined packed-B MFMA GEMM with split-K support (weight GEMMs).
// ---------------------------------------------------------------------------
template<int BM, int BN, int ACT>
__global__ __launch_bounds__(256)
void gemm_mfma_pb(const float* __restrict__ A, int lda, long sA,
                  const unsigned short* __restrict__ Bp, int Np, long sBp,
                  float* __restrict__ C, int ldc, long sC,
                  const float* __restrict__ bias, long sBias,
                  int K, float alpha, int ksl, long sSlice)
{
    constexpr int BK = 32;
    constexpr int PK = 40;              // 80B row stride
    constexpr int FM = BM / 32;
    constexpr int FN = BN / 32;
    constexpr int NA = BM / 32;

    __shared__ __align__(16) unsigned short Ah0[BM][PK], Al0[BM][PK];
    __shared__ __align__(16) unsigned short Ah1[BM][PK], Al1[BM][PK];

    int bx, by, bz;
    xcd_decode(bx, by, bz);
    const int zb = bz / ksl, ks = bz - zb * ksl;
    const int kLen = K / ksl, k0 = ks * kLen;
    const int nit = kLen / BK;          // even at every call site

    const int tid  = threadIdx.x;
    const int lane = tid & 63;
    const int wave = tid >> 6;
    const int wm   = (wave >> 1) * (BM / 2);
    const int wn   = (wave & 1)  * (BN / 2);
    const int lr   = lane & 15;
    const int ko   = (lane >> 4) * 8;

    const float* Abase = A + (long)zb * sA;
    const unsigned short* Bb = Bp + (long)zb * sBp;
    float* Cbase = C + (long)zb * sC + (long)ks * sSlice;
    const int n0  = bx * BN;
    const int m0  = by * BM;
    const int nch = Np >> 4;
    const int cb  = (n0 + wn) >> 4;

    f32x4 acc[FM][FN];
#pragma unroll
    for (int i = 0; i < FM; ++i)
#pragma unroll
        for (int j = 0; j < FN; ++j) acc[i][j] = f32x4{0.f, 0.f, 0.f, 0.f};

    const int akq = tid & 7;
    const int amr = tid >> 3;

    auto loadA = [&](int kt, float4* pa) {
#pragma unroll
        for (int r = 0; r < NA; ++r)
            pa[r] = *(const float4*)(Abase + (long)(m0 + r * 32 + amr) * lda + kt + akq * 4);
    };
    auto storeA = [&](unsigned short (*AhD)[PK], unsigned short (*AlD)[PK],
                      const float4* pa) {
#pragma unroll
        for (int r = 0; r < NA; ++r) {
            ushort4 h, l;
            split1(pa[r].x, h.x, l.x); split1(pa[r].y, h.y, l.y);
            split1(pa[r].z, h.z, l.z); split1(pa[r].w, h.w, l.w);
            *(ushort4*)&AhD[r * 32 + amr][akq * 4] = h;
            *(ushort4*)&AlD[r * 32 + amr][akq * 4] = l;
        }
    };
    auto loadB = [&](int kt, bf16x8* h, bf16x8* l) {
        const unsigned short* p = Bb + ((long)(kt >> 5) * nch + cb) * 1024 + (lane << 3);
#pragma unroll
        for (int ni = 0; ni < FN; ++ni) {
            h[ni] = *(const bf16x8*)(p + ni * 1024);
            l[ni] = *(const bf16x8*)(p + ni * 1024 + 512);
        }
    };
    auto mmaStep = [&](unsigned short (*AhS)[PK], unsigned short (*AlS)[PK],
                       const bf16x8* bh, const bf16x8* bl) {
        bf16x8 ah[FM], al[FM];
#pragma unroll
        for (int mi = 0; mi < FM; ++mi) {
            ah[mi] = *(const bf16x8*)&AhS[wm + mi * 16 + lr][ko];
            al[mi] = *(const bf16x8*)&AlS[wm + mi * 16 + lr][ko];
        }
#pragma unroll
        for (int mi = 0; mi < FM; ++mi)
#pragma unroll
            for (int ni = 0; ni < FN; ++ni) {
                acc[mi][ni] = __builtin_amdgcn_mfma_f32_16x16x32_bf16(
                    ah[mi], bh[ni], acc[mi][ni], 0, 0, 0);
                acc[mi][ni] = __builtin_amdgcn_mfma_f32_16x16x32_bf16(
                    ah[mi], bl[ni], acc[mi][ni], 0, 0, 0);
                acc[mi][ni] = __builtin_amdgcn_mfma_f32_16x16x32_bf16(
                    al[mi], bh[ni], acc[mi][ni], 0, 0, 0);
            }
    };
    auto bar = [&]() {
        asm volatile("s_waitcnt lgkmcnt(0)" ::: "memory");
        __builtin_amdgcn_s_barrier();
    };

    float4 paA[NA], paB[NA];
    bf16x8 bhE[FN], blE[FN], bhO[FN], blO[FN];

    loadA(k0, paA);
    loadB(k0, bhE, blE);
    loadA(k0 + BK, paB);
    storeA(Ah0, Al0, paA);
    loadB(k0 + BK, bhO, blO);
    bar();

    for (int t = 0; t < nit; t += 2) {
        if (t + 2 < nit) loadA(k0 + (t + 2) * BK, paA);
        mmaStep(Ah0, Al0, bhE, blE);
        if (t + 2 < nit) loadB(k0 + (t + 2) * BK, bhE, blE);
        storeA(Ah1, Al1, paB);
        bar();
        if (t + 3 < nit) loadA(k0 + (t + 3) * BK, paB);
        mmaStep(Ah1, Al1, bhO, blO);
        if (t + 3 < nit) loadB(k0 + (t + 3) * BK, bhO, blO);
        if (t + 2 < nit) {
            storeA(Ah0, Al0, paA);
            bar();
        }
    }

    float bv[FN];
#pragma unroll
    for (int ni = 0; ni < FN; ++ni)
        bv[ni] = (bias && ks == 0)
               ? bias[(long)zb * sBias + n0 + wn + ni * 16 + lr] : 0.f;
    const int cr = (lane >> 4) * 4;
#pragma unroll
    for (int mi = 0; mi < FM; ++mi)
#pragma unroll
        for (int ni = 0; ni < FN; ++ni) {
#pragma unroll
            for (int r = 0; r < 4; ++r) {
                float t = acc[mi][ni][r] * alpha + bv[ni];
                if (ACT == 1) t = fmaxf(t, 0.f);
                else if (ACT == 2) t = tanhf(t);
                Cbase[(long)(m0 + wm + mi * 16 + cr + r) * ldc
                      + n0 + wn + ni * 16 + lr] = t;
            }
        }
}

// ---------------------------------------------------------------------------
// Dynamic-B split-bf16 MFMA GEMM (QK^T and PV; BT=true).
// MODE: 0 = full; 1 = QK^T band skip (return if tile fully masked);
//       2 = PV banded K-range (exact: P==0 outside band).
// ---------------------------------------------------------------------------
template<int BM, int BN, int ACT, bool BT, int MODE>
__global__ __launch_bounds__(256)
void gemm_mfma(const float* __restrict__ A, int lda, long sA,
               const float* __restrict__ B, int ldb, long sB,
               float* __restrict__ C, int ldc, long sC,
               const float* __restrict__ bias, long sBias,
               int K, float alpha, const int* __restrict__ winp)
{
    constexpr int BK = 32;
    constexpr int PK = 40;
    constexpr int FM = BM / 32;
    constexpr int FN = BN / 32;
    constexpr int NA = BM / 32;
    constexpr int NB = BN / 32;

    __shared__ __align__(16) unsigned short Ah[BM][PK], Al[BM][PK];
    __shared__ __align__(16) unsigned short Bh[BN][PK], Bl[BN][PK];

    int bx, by, bz;
    xcd_decode(bx, by, bz);

    const int n0 = bx * BN;
    const int m0 = by * BM;

    int klo = 0, khi = K;
    if constexpr (MODE == 1) {
        const int w = winp[0];
        if (n0 > m0 + (BM - 1) + w || m0 > n0 + (BN - 1) + w) return;
    } else if constexpr (MODE == 2) {
        const int w = winp[0];
        klo = (m0 > w) ? ((m0 - w) & ~31) : 0;
        khi = (m0 + BM + w + 31) & ~31;
        if (khi > K) khi = K;
    }

    const int tid  = threadIdx.x;
    const int lane = tid & 63;
    const int wave = tid >> 6;
    const int wm   = (wave >> 1) * (BM / 2);
    const int wn   = (wave & 1)  * (BN / 2);
    const int lr   = lane & 15;
    const int ko   = (lane >> 4) * 8;

    const float* Abase = A + (long)bz * sA;
    const float* Bbase = B + (long)bz * sB;
    float*       Cbase = C + (long)bz * sC;

    f32x4 acc[FM][FN];
#pragma unroll
    for (int i = 0; i < FM; ++i)
#pragma unroll
        for (int j = 0; j < FN; ++j) acc[i][j] = f32x4{0.f, 0.f, 0.f, 0.f};

    const int akq = tid & 7;
    const int amr = tid >> 3;

    auto loadA = [&](int kt, float4* pa) {
#pragma unroll
        for (int r = 0; r < NA; ++r)
            pa[r] = *(const float4*)(Abase + (long)(m0 + r * 32 + amr) * lda + kt + akq * 4);
    };
    auto loadB = [&](int kt, float4* pb) {
#pragma unroll
        for (int r = 0; r < NB; ++r)
            pb[r] = *(const float4*)(Bbase + (long)(n0 + r * 32 + amr) * ldb + kt + akq * 4);
    };
    auto storeA = [&](const float4* pa) {
#pragma unroll
        for (int r = 0; r < NA; ++r) {
            ushort4 h, l;
            split1(pa[r].x, h.x, l.x); split1(pa[r].y, h.y, l.y);
            split1(pa[r].z, h.z, l.z); split1(pa[r].w, h.w, l.w);
            *(ushort4*)&Ah[r * 32 + amr][akq * 4] = h;
            *(ushort4*)&Al[r * 32 + amr][akq * 4] = l;
        }
    };
    auto storeB = [&](const float4* pb) {
#pragma unroll
        for (int r = 0; r < NB; ++r) {
            ushort4 h, l;
            split1(pb[r].x, h.x, l.x); split1(pb[r].y, h.y, l.y);
            split1(pb[r].z, h.z, l.z); split1(pb[r].w, h.w, l.w);
            *(ushort4*)&Bh[r * 32 + amr][akq * 4] = h;
            *(ushort4*)&Bl[r * 32 + amr][akq * 4] = l;
        }
    };

    float4 pa[NA], pb[NB];
    loadA(klo, pa); loadB(klo, pb);

    for (int kt = klo; kt < khi; kt += BK) {
        storeA(pa);
        storeB(pb);
        __syncthreads();

        const bool more = kt + BK < khi;
        float4 na[NA], nb[NB];
        if (more) { loadA(kt + BK, na); loadB(kt + BK, nb); }

        bf16x8 ah[FM], al[FM], bh[FN], bl[FN];
#pragma unroll
        for (int mi = 0; mi < FM; ++mi) {
            ah[mi] = *(const bf16x8*)&Ah[wm + mi * 16 + lr][ko];
            al[mi] = *(const bf16x8*)&Al[wm + mi * 16 + lr][ko];
        }
#pragma unroll
        for (int ni = 0; ni < FN; ++ni) {
            bh[ni] = *(const bf16x8*)&Bh[wn + ni * 16 + lr][ko];
            bl[ni] = *(const bf16x8*)&Bl[wn + ni * 16 + lr][ko];
        }
#pragma unroll
        for (int mi = 0; mi < FM; ++mi)
#pragma unroll
            for (int ni = 0; ni < FN; ++ni) {
                acc[mi][ni] = __builtin_amdgcn_mfma_f32_16x16x32_bf16(
                    ah[mi], bh[ni], acc[mi][ni], 0, 0, 0);
                acc[mi][ni] = __builtin_amdgcn_mfma_f32_16x16x32_bf16(
                    ah[mi], bl[ni], acc[mi][ni], 0, 0, 0);
                acc[mi][ni] = __builtin_amdgcn_mfma_f32_16x16x32_bf16(
                    al[mi], bh[ni], acc[mi][ni], 0, 0, 0);
            }
        __syncthreads();

        if (more) {
#pragma unroll
            for (int r = 0; r < NA; ++r) pa[r] = na[r];
#pragma unroll
            for (int r = 0; r < NB; ++r) pb[r] = nb[r];
        }
    }

    float bv[FN];
#pragma unroll
    for (int ni = 0; ni < FN; ++ni)
        bv[ni] = bias ? bias[(long)bz * sBias + n0 + wn + ni * 16 + lr] : 0.f;
    const int cr = (lane >> 4) * 4;
#pragma unroll
    for (int mi = 0; mi < FM; ++mi)
#pragma unroll
        for (int ni = 0; ni < FN; ++ni) {
#pragma unroll
            for (int r = 0; r < 4; ++r) {
                float t = acc[mi][ni][r] * alpha + bv[ni];
                if (ACT == 1) t = fmaxf(t, 0.f);
                else if (ACT == 2) t = tanhf(t);
                Cbase[(long)(m0 + wm + mi * 16 + cr + r) * ldc
                      + n0 + wn + ni * 16 + lr] = t;
            }
        }
}

// ---------------------------------------------------------------------------
// vt[b][c][l] = qkv[b][l][2048 + c]
// ---------------------------------------------------------------------------
__global__ __launch_bounds__(256)
void vtrans_kernel(const float* __restrict__ qkv, float* __restrict__ vt)
{
    __shared__ float t[32][33];
    const int b  = blockIdx.z;
    const int l0 = blockIdx.x * 32, c0 = blockIdx.y * 32;
    const int tx = threadIdx.x & 31, ty = threadIdx.x >> 5;
    const float* src = qkv + (long)b * 3 * LD + 2048;
#pragma unroll
    for (int r = ty; r < 32; r += 8)
        t[r][tx] = src[(long)(l0 + r) * 3072 + c0 + tx];
    __syncthreads();
    float* dst = vt + (long)b * LD;
#pragma unroll
    for (int r = ty; r < 32; r += 8)
        dst[(long)(c0 + r) * L + l0 + tx] = t[tx][r];
}

// ---------------------------------------------------------------------------
__global__ void add_pe_kernel(const float* __restrict__ src, float* __restrict__ x)
{
    long idx = (long)blockIdx.x * 256 + threadIdx.x;   // < LD
    int pos = (int)(idx >> 10);
    int d   = (int)(idx & 1023);
    float expnt = (float)(d & ~1) * (1.0f / (float)D);
    float denom = powf(10000.0f, expnt);
    float ang   = (float)pos / denom;
    float pe    = (d & 1) ? cosf(ang) : sinf(ang);
    float v = src[idx] + pe;
    x[idx]          = v;
    x[LD + idx]     = v;
    x[2 * LD + idx] = v;
}

// ---------------------------------------------------------------------------
// Banded masked softmax. Row i only has unmasked cols in [i-w, i+w]; PV only
// reads the tile-aligned range [kmin, khi) for q-tile ti = i>>6, so we only
// load/mask/normalize/write that range. Masked entries use SELECT (not add),
// so never-written S tiles (incl. NaN poison) are harmless; masked in-range
// cols get exact 0 written.
// ---------------------------------------------------------------------------
__global__ __launch_bounds__(256)
void softmax_mask_kernel(float* __restrict__ S, const int* __restrict__ utt,
                         const int* __restrict__ spk, const int* __restrict__ winp,
                         int branch)
{
    __shared__ float red[8];
    const int i   = blockIdx.x;
    const int h   = blockIdx.y;
    const int tid = threadIdx.x;
    float* row = S + ((long)h * L + i) * L;
    const int w    = winp[0];
    const int ti   = i >> 6;
    const int kmin = (ti * 64 > w) ? (((ti * 64 - w) >> 5) << 5) : 0;
    int khi = (ti * 64 + 64 + w + 31) & ~31;
    if (khi > L) khi = L;
    const int utti = utt[i];
    const int spki = spk[i];
    const int j0 = kmin + tid * 4;
    const bool act = j0 < khi;

    float s[4] = {-1e9f, -1e9f, -1e9f, -1e9f};
    if (act) {
        float4 sv = *(float4*)(row + j0);
        float svv[4] = {sv.x, sv.y, sv.z, sv.w};
#pragma unroll
        for (int c = 0; c < 4; ++c) {
            int j = j0 + c;
            int dd = j - i;
            bool win  = (dd <= w) && (-dd <= w);
            bool base = win && (utti > 0) && (utt[j] > 0);
            bool same = (spk[j] == spki);
            bool keep = (branch == 0) ? base
                      : (branch == 1) ? (base && same)
                      : (base && (!same || (j == i)));
            s[c] = keep ? svv[c] : -1e9f;
        }
    }
    float mx = fmaxf(fmaxf(s[0], s[1]), fmaxf(s[2], s[3]));
    for (int off = 32; off; off >>= 1) mx = fmaxf(mx, __shfl_xor(mx, off));
    if ((tid & 63) == 0) red[tid >> 6] = mx;
    __syncthreads();
    mx = fmaxf(fmaxf(red[0], red[1]), fmaxf(red[2], red[3]));
    __syncthreads();

    float e[4]; float sum = 0.f;
#pragma unroll
    for (int c = 0; c < 4; ++c) { e[c] = expf(s[c] - mx); sum += e[c]; }
    for (int off = 32; off; off >>= 1) sum += __shfl_xor(sum, off);
    if ((tid & 63) == 0) red[tid >> 6] = sum;
    __syncthreads();
    float inv = 1.f / (red[0] + red[1] + red[2] + red[3]);

    if (act) {
        float4 o = {e[0] * inv, e[1] * inv, e[2] * inv, e[3] * inv};
        *(float4*)(row + j0) = o;
    }
}

// ---------------------------------------------------------------------------
// LayerNorm: out = LN(x + sum_{s<nslc} r[s]) * g + b
// ---------------------------------------------------------------------------
__global__ __launch_bounds__(256)
void ln_kernel(const float* __restrict__ x, const float* __restrict__ r,
               int nslc, long sSlice,
               const float* __restrict__ g, const float* __restrict__ b,
               float* __restrict__ out, long paramStride)
{
    __shared__ float red[8];
    const int row = blockIdx.x;
    const int grp = row >> 10;
    const int tid = threadIdx.x;
    const long base = (long)row * D + tid * 4;

    float4 t = *(const float4*)(x + base);
    for (int s = 0; s < nslc; ++s) {
        float4 rv = *(const float4*)(r + (long)s * sSlice + base);
        t.x += rv.x; t.y += rv.y; t.z += rv.z; t.w += rv.w;
    }

    float sm = t.x + t.y + t.z + t.w;
    for (int off = 32; off; off >>= 1) sm += __shfl_xor(sm, off);
    if ((tid & 63) == 0) red[tid >> 6] = sm;
    __syncthreads();
    float mean = (red[0] + red[1] + red[2] + red[3]) * (1.f / (float)D);
    __syncthreads();

    float4 dv = {t.x - mean, t.y - mean, t.z - mean, t.w - mean};
    float sq = dv.x * dv.x + dv.y * dv.y + dv.z * dv.z + dv.w * dv.w;
    for (int off = 32; off; off >>= 1) sq += __shfl_xor(sq, off);
    if ((tid & 63) == 0) red[tid >> 6] = sq;
    __syncthreads();
    float var  = (red[0] + red[1] + red[2] + red[3]) * (1.f / (float)D);
    float rstd = rsqrtf(var + 1e-5f);

    const float* gp = g + (long)grp * paramStride + tid * 4;
    const float* bp = b + (long)grp * paramStride + tid * 4;
    float4 gv = *(const float4*)gp;
    float4 bv = *(const float4*)bp;
    float4 o = {dv.x * rstd * gv.x + bv.x, dv.y * rstd * gv.y + bv.y,
                dv.z * rstd * gv.z + bv.z, dv.w * rstd * gv.w + bv.w};
    *(float4*)(out + base) = o;
}

// ---------------------------------------------------------------------------
// s[row] = dot(tanh(sum_slices t[row]), v); rows = 2*L
// ---------------------------------------------------------------------------
__global__ __launch_bounds__(256)
void rowdot_kernel(const float* __restrict__ t, long sSlice, int nslc,
                   const float* __restrict__ v, float* __restrict__ s)
{
    __shared__ float red[8];
    const int row = blockIdx.x;
    const int tid = threadIdx.x;
    const long base = (long)row * D + tid * 4;
    float4 a = *(const float4*)(t + base);
    for (int sl = 1; sl < nslc; ++sl) {
        float4 a2 = *(const float4*)(t + (long)sl * sSlice + base);
        a.x += a2.x; a.y += a2.y; a.z += a2.z; a.w += a2.w;
    }
    a.x = tanhf(a.x); a.y = tanhf(a.y); a.z = tanhf(a.z); a.w = tanhf(a.w);
    float4 vv = *(const float4*)(v + tid * 4);
    float p = a.x * vv.x + a.y * vv.y + a.z * vv.z + a.w * vv.w;
    for (int off = 32; off; off >>= 1) p += __shfl_xor(p, off);
    if ((tid & 63) == 0) red[tid >> 6] = p;
    __syncthreads();
    if (tid == 0) s[row] = red[0] + red[1] + red[2] + red[3];
}

// ---------------------------------------------------------------------------
__global__ void combine_kernel(const float* __restrict__ sb, const float* __restrict__ h,
                               float* __restrict__ out)
{
    long idx = (long)blockIdx.x * 256 + threadIdx.x;   // < LD
    int l = (int)(idx >> 10);
    float s0 = sb[l], s1 = sb[L + l];
    float m  = fmaxf(s0, s1);
    float e0 = expf(s0 - m), e1 = expf(s1 - m);
    float inv = 1.f / (e0 + e1);
    out[idx] = (e0 * h[idx] + e1 * h[LD + idx]) * inv;
}

// ---------------------------------------------------------------------------
__global__ __launch_bounds__(256)
void cls_kernel(const float* __restrict__ x, const float* __restrict__ W,
                const float* __restrict__ b, float* __restrict__ out)
{
    __shared__ float red[4][7];
    __shared__ float logit[7];
    const int row = blockIdx.x;
    const int tid = threadIdx.x;
    float p[7] = {0, 0, 0, 0, 0, 0, 0};
    for (int d = tid; d < D; d += 256) {
        float xv = x[(long)row * D + d];
#pragma unroll
        for (int c = 0; c < 7; ++c) p[c] = fmaf(xv, W[d * 7 + c], p[c]);
    }
#pragma unroll
    for (int c = 0; c < 7; ++c) {
        float v = p[c];
        for (int off = 32; off; off >>= 1) v += __shfl_xor(v, off);
        if ((tid & 63) == 0) red[tid >> 6][c] = v;
    }
    __syncthreads();
    if (tid < 7)
        logit[tid] = red[0][tid] + red[1][tid] + red[2][tid] + red[3][tid] + b[tid];
    __syncthreads();
    if (tid == 0) {
        float mx = logit[0];
        for (int c = 1; c < 7; ++c) mx = fmaxf(mx, logit[c]);
        float sum = 0.f;
        for (int c = 0; c < 7; ++c) sum += expf(logit[c] - mx);
        float lse = logf(sum) + mx;
        for (int c = 0; c < 7; ++c) out[(long)row * 7 + c] = logit[c] - lse;
    }
}

} // anonymous namespace

extern "C" void kernel_launch(void* const* d_in, const int* in_sizes, int n_in,
                              void* d_out, int out_size, void* d_ws, size_t ws_size,
                              hipStream_t stream)
{
    (void)in_sizes; (void)n_in; (void)out_size; (void)ws_size;

    const float* src  = (const float*)d_in[0];
    const int*   utt  = (const int*)d_in[1];
    const int*   spk  = (const int*)d_in[2];
    const int*   winp = (const int*)d_in[3];
    const float* Wqkv = (const float*)d_in[4];
    const float* bqkv = (const float*)d_in[5];
    const float* Wo   = (const float*)d_in[6];
    const float* bo   = (const float*)d_in[7];
    const float* g1   = (const float*)d_in[8];
    const float* b1   = (const float*)d_in[9];
    const float* Wf1  = (const float*)d_in[10];
    const float* bf1  = (const float*)d_in[11];
    const float* Wf2  = (const float*)d_in[12];
    const float* bf2  = (const float*)d_in[13];
    const float* g2   = (const float*)d_in[14];
    const float* b2   = (const float*)d_in[15];
    const float* f1W  = (const float*)d_in[16];
    const float* f1b  = (const float*)d_in[17];
    const float* f1v  = (const float*)d_in[18];
    const float* f2W  = (const float*)d_in[19];
    const float* f2b  = (const float*)d_in[20];
    const float* f2v  = (const float*)d_in[21];
    const float* clsW = (const float*)d_in[22];
    const float* clsb = (const float*)d_in[23];
    float* out = (float*)d_out;

    // ---- workspace arena (floats) ----
    float* ws    = (float*)d_ws;
    float* x     = ws;               // 3*LD
    float* qkv   = x + 3 * LD;       // 9*LD ; later FFN2 slice scratch
    float* attno = qkv + 9 * LD;     // 3*LD
    float* tmp   = attno + 3 * LD;   // 3*LD ; vt during attention; fusion out
    float* R1    = tmp + 3 * LD;     // 16*LD  S / slices / ffn
    float* sbuf  = R1 + 16 * LD;     // 2*L
    float* S    = R1;                // [16][L][L] scores (attention phase)
    float* ffn  = R1;                // [3][L][DFF] (FFN phase)
    float* vt   = tmp;               // [3][D][L] transposed V (attention phase)
    float* f2s  = qkv;               // [4][3][L][D] FFN2 slices
    float* h2   = R1 + 4 * LD;       // [2][L][D] (fusion phase)
    unsigned short* wpack = (unsigned short*)(sbuf + 2 * L);

    add_pe_kernel<<<LD / 256, 256, 0, stream>>>(src, x);

    for (int l = 0; l < NL; ++l) {
        // QKV projection
        repack_w<<<dim3(6144 / 4, 3), 256, 0, stream>>>(
            Wqkv + (long)l * D * 3 * D, 3 * D, (long)NL * D * 3 * D,
            wpack, (long)2 * D * 3 * D, 3 * D);
        gemm_mfma_pb<128, 128, 0>
            <<<dim3(3 * D / 128, L / 128, 3), 256, 0, stream>>>(
            x, D, LD, wpack, 3 * D, (long)2 * D * 3 * D,
            qkv, 3 * D, 3 * LD, bqkv + (long)l * 3 * D, (long)NL * 3 * D,
            D, 1.f, 1, 0);

        vtrans_kernel<<<dim3(L / 32, D / 32, 3), 256, 0, stream>>>(qkv, vt);

        for (int b = 0; b < 3; ++b) {
            const float* qkvb = qkv + (long)b * 3 * LD;
            // scores: banded QK^T (skips fully-masked 128x128 tiles)
            gemm_mfma<128, 128, 0, true, 1>
                <<<dim3(L / 128, L / 128, NH), 256, 0, stream>>>(
                qkvb, 3 * D, 64, qkvb + D, 3 * D, 64,
                S, L, (long)L * L, nullptr, 0, DH, 0.125f, winp);
            softmax_mask_kernel<<<dim3(L, NH), 256, 0, stream>>>(S, utt, spk, winp, b);
            // O = P @ V^T-rows, banded K-range (exact: P==0 outside band)
            gemm_mfma<64, 64, 0, true, 2>
                <<<dim3(1, L / 64, NH), 256, 0, stream>>>(
                S, L, (long)L * L, vt + (long)b * LD, L, (long)64 * L,
                attno + (long)b * LD, D, 64, nullptr, 0, L, 1.f, winp);
        }

        // output projection, split-K=4
        repack_w<<<dim3(2048 / 4, 3), 256, 0, stream>>>(
            Wo + (long)l * D * D, D, (long)NL * D * D,
            wpack, (long)2 * D * D, D);
        gemm_mfma_pb<128, 128, 0>
            <<<dim3(D / 128, L / 128, 12), 256, 0, stream>>>(
            attno, D, LD, wpack, D, (long)2 * D * D,
            R1, D, LD, bo + (long)l * D, (long)NL * D,
            D, 1.f, 4, (long)3 * LD);
        ln_kernel<<<3 * L, 256, 0, stream>>>(x, R1, 4, (long)3 * LD,
                                             g1 + (long)l * D, b1 + (long)l * D,
                                             x, (long)NL * D);
        // FFN1 (relu)
        repack_w<<<dim3(8192 / 4, 3), 256, 0, stream>>>(
            Wf1 + (long)l * D * DFF, DFF, (long)NL * D * DFF,
            wpack, (long)2 * D * DFF, DFF);
        gemm_mfma_pb<128, 128, 1>
            <<<dim3(DFF / 128, L / 128, 3), 256, 0, stream>>>(
            x, D, LD, wpack, DFF, (long)2 * D * DFF,
            ffn, DFF, (long)L * DFF, bf1 + (long)l * DFF, (long)NL * DFF,
            D, 1.f, 1, 0);
        // FFN2, split-K=4
        repack_w<<<dim3(8192 / 4, 3), 256, 0, stream>>>(
            Wf2 + (long)l * DFF * D, D, (long)NL * DFF * D,
            wpack, (long)2 * DFF * D, D);
        gemm_mfma_pb<128, 128, 0>
            <<<dim3(D / 128, L / 128, 12), 256, 0, stream>>>(
            ffn, DFF, (long)L * DFF, wpack, D, (long)2 * DFF * D,
            f2s, D, LD, bf2 + (long)l * D, (long)NL * D,
            DFF, 1.f, 4, (long)3 * LD);
        ln_kernel<<<3 * L, 256, 0, stream>>>(x, f2s, 4, (long)3 * LD,
                                             g2 + (long)l * D, b2 + (long)l * D,
                                             x, (long)NL * D);
    }

    // ---- fusion 1 ----
    repack_w<<<dim3(2048 / 4, 1), 256, 0, stream>>>(f1W, D, 0, wpack, 0, D);
    gemm_mfma_pb<128, 128, 0>
        <<<dim3(D / 128, L / 128, 4), 256, 0, stream>>>(
        x + LD, D, LD, wpack, D, 0, R1, D, LD, f1b, 0, D, 1.f, 2, (long)2 * LD);
    rowdot_kernel<<<2 * L, 256, 0, stream>>>(R1, (long)2 * LD, 2, f1v, sbuf);
    combine_kernel<<<LD / 256, 256, 0, stream>>>(sbuf, x + LD, h2 + LD);   // sp -> h2[1]
    hipMemcpyAsync(h2, x, LD * sizeof(float), hipMemcpyDeviceToDevice, stream); // ct

    // ---- fusion 2 ----
    repack_w<<<dim3(2048 / 4, 1), 256, 0, stream>>>(f2W, D, 0, wpack, 0, D);
    gemm_mfma_pb<128, 128, 0>
        <<<dim3(D / 128, L / 128, 4), 256, 0, stream>>>(
        h2, D, LD, wpack, D, 0, R1, D, LD, f2b, 0, D, 1.f, 2, (long)2 * LD);
    rowdot_kernel<<<2 * L, 256, 0, stream>>>(R1, (long)2 * LD, 2, f2v, sbuf);
    combine_kernel<<<LD / 256, 256, 0, stream>>>(sbuf, h2, tmp);           // fused -> tmp

    // ---- classifier + log_softmax ----
    cls_kernel<<<L, 256, 0, stream>>>(tmp, clsW, clsb, out);
}

// Round 6
// 1902.754 us; speedup vs baseline: 1.4221x; 1.1932x over previous
//
#include <hip/hip_runtime.h>
#include <cmath>

namespace {

constexpr int L   = 1024;
constexpr int D   = 1024;
constexpr int DFF = 4096;
constexpr int NL  = 3;
constexpr int NH  = 16;
constexpr int DH  = 64;
constexpr long LD = (long)L * D;   // 1048576

typedef __attribute__((ext_vector_type(8))) short bf16x8;  // 8 bf16 (4 VGPRs)
typedef __attribute__((ext_vector_type(4))) float f32x4;   // MFMA C/D

// Split fp32 into hi/lo bf16 (truncation split)
__device__ inline void split1(float f, unsigned short& h, unsigned short& l)
{
    unsigned u = __float_as_uint(f);
    h = (unsigned short)(u >> 16);
    float hf = __uint_as_float(u & 0xffff0000u);
    l = (unsigned short)(__float_as_uint(f - hf) >> 16);
}

// Bijective XCD-chunk swizzle of the flat block index (requires nwg % 8 == 0).
__device__ inline void xcd_decode(int& bx, int& by, int& bz)
{
    const int gx = gridDim.x, gy = gridDim.y;
    const int nwg = gx * gy * gridDim.z;
    int flat = blockIdx.x + gx * (blockIdx.y + gy * blockIdx.z);
    int w = (flat & 7) * (nwg >> 3) + (flat >> 3);
    bz = w / (gx * gy);
    int rem = w - bz * gx * gy;
    by = rem / gx;
    bx = rem - by * gx;
}

// ---------------------------------------------------------------------------
// Weight repack: fp32 [K x N] -> fragment-ordered hi/lo bf16 (2KB chunks).
// Coalesced: stage a 32k x 128n fp32 tile through LDS (1KB/instr global
// loads), then pack 8 chunks per block. Chunk (k32,n16): lane = n%16 +
// ((k%32)/8)*16 holds its 8-k octet; hi at lane*8, lo at 512+lane*8.
// ---------------------------------------------------------------------------
__global__ __launch_bounds__(256)
void repack_w(const float* __restrict__ W, int ldw, long sW,
              unsigned short* __restrict__ out, long sOut, int Np)
{
    __shared__ float lds[32][129];   // +1 pad: oct-group reads 2-way max
    const int t = threadIdx.x;
    const int ntile = Np >> 7;            // N/128 tiles per k-row
    const int kt = blockIdx.x / ntile, nt = blockIdx.x % ntile;
    const int z = blockIdx.y;
    const float* Wz = W + (long)z * sW + (long)(kt * 32) * ldw + nt * 128;
    const int q = t & 31, rg = t >> 5;
#pragma unroll
    for (int i = 0; i < 4; ++i) {
        int r = rg * 4 + i;
        *(float4*)&lds[r][q * 4] = *(const float4*)(Wz + (long)r * ldw + q * 4);
    }
    __syncthreads();
    const int lane = t & 63, wave = t >> 6;
    const int nch = Np >> 4;
#pragma unroll
    for (int j = 0; j < 2; ++j) {
        int ci = wave * 2 + j;
        int n  = ci * 16 + (lane & 15);
        int oct = lane >> 4;
        unsigned short h[8], l[8];
#pragma unroll
        for (int e = 0; e < 8; ++e)
            split1(lds[oct * 8 + e][n], h[e], l[e]);
        unsigned short* oz = out + (long)z * sOut
            + ((long)kt * nch + nt * 8 + ci) * 1024 + (lane << 3);
        *(ushort4*)(oz)       = *(ushort4*)&h[0];
        *(ushort4*)(oz + 4)   = *(ushort4*)&h[4];
        *(ushort4*)(oz + 512) = *(ushort4*)&l[0];
        *(ushort4*)(oz + 516) = *(ushort4*)&l[4];
    }
}

// ---------------------------------------------------------------------------
// Pipelined packed-B MFMA GEMM, wide-N wave tile (64x128), split-K support.
//  - A fp32 [M x K], staged hi/lo bf16 through double-buffered LDS
//  - B pre-packed fragment-order (repack_w), global->regs, no LDS, single-
//    buffered (reloaded after consumption; vmcnt counted by compiler)
//  4 waves in 2x2; FM=4, FN=8; acc 128 VGPR; __launch_bounds__(256,2).
// ---------------------------------------------------------------------------
template<int BM, int BN, int ACT>
__global__ __launch_bounds__(256, 2)
void gemm_mfma_pb(const float* __restrict__ A, int lda, long sA,
                  const unsigned short* __restrict__ Bp, int Np, long sBp,
                  float* __restrict__ C, int ldc, long sC,
                  const float* __restrict__ bias, long sBias,
                  int K, float alpha, int ksl, long sSlice)
{
    constexpr int BK = 32;
    constexpr int PK = 40;              // 80B row stride
    constexpr int FM = BM / 32;         // wave M frags (wave covers BM/2)
    constexpr int FN = BN / 32;         // wave N frags (wave covers BN/2)
    constexpr int NA = BM / 32;         // A float4 loads per thread

    __shared__ __align__(16) unsigned short Ah0[BM][PK], Al0[BM][PK];
    __shared__ __align__(16) unsigned short Ah1[BM][PK], Al1[BM][PK];

    int bx, by, bz;
    xcd_decode(bx, by, bz);
    const int zb = bz / ksl, ks = bz - zb * ksl;
    const int kLen = K / ksl, k0 = ks * kLen;
    const int nit = kLen / BK;          // even at every call site

    const int tid  = threadIdx.x;
    const int lane = tid & 63;
    const int wave = tid >> 6;
    const int wm   = (wave >> 1) * (BM / 2);
    const int wn   = (wave & 1)  * (BN / 2);
    const int lr   = lane & 15;
    const int ko   = (lane >> 4) * 8;

    const float* Abase = A + (long)zb * sA;
    const unsigned short* Bb = Bp + (long)zb * sBp;
    float* Cbase = C + (long)zb * sC + (long)ks * sSlice;
    const int n0  = bx * BN;
    const int m0  = by * BM;
    const int nch = Np >> 4;
    const int cb  = (n0 + wn) >> 4;

    f32x4 acc[FM][FN];
#pragma unroll
    for (int i = 0; i < FM; ++i)
#pragma unroll
        for (int j = 0; j < FN; ++j) acc[i][j] = f32x4{0.f, 0.f, 0.f, 0.f};

    const int akq = tid & 7;
    const int amr = tid >> 3;

    auto loadA = [&](int kt, float4* pa) {
#pragma unroll
        for (int r = 0; r < NA; ++r)
            pa[r] = *(const float4*)(Abase + (long)(m0 + r * 32 + amr) * lda + kt + akq * 4);
    };
    auto storeA = [&](unsigned short (*AhD)[PK], unsigned short (*AlD)[PK],
                      const float4* pa) {
#pragma unroll
        for (int r = 0; r < NA; ++r) {
            ushort4 h, l;
            split1(pa[r].x, h.x, l.x); split1(pa[r].y, h.y, l.y);
            split1(pa[r].z, h.z, l.z); split1(pa[r].w, h.w, l.w);
            *(ushort4*)&AhD[r * 32 + amr][akq * 4] = h;
            *(ushort4*)&AlD[r * 32 + amr][akq * 4] = l;
        }
    };
    auto loadB = [&](int kt, bf16x8* h, bf16x8* l) {
        const unsigned short* p = Bb + ((long)(kt >> 5) * nch + cb) * 1024 + (lane << 3);
#pragma unroll
        for (int ni = 0; ni < FN; ++ni) {
            h[ni] = *(const bf16x8*)(p + ni * 1024);
            l[ni] = *(const bf16x8*)(p + ni * 1024 + 512);
        }
    };
    auto mmaStep = [&](unsigned short (*AhS)[PK], unsigned short (*AlS)[PK],
                       const bf16x8* bh, const bf16x8* bl) {
#pragma unroll
        for (int mi = 0; mi < FM; ++mi) {
            bf16x8 ah = *(const bf16x8*)&AhS[wm + mi * 16 + lr][ko];
            bf16x8 al = *(const bf16x8*)&AlS[wm + mi * 16 + lr][ko];
#pragma unroll
            for (int ni = 0; ni < FN; ++ni) {
                acc[mi][ni] = __builtin_amdgcn_mfma_f32_16x16x32_bf16(
                    ah, bh[ni], acc[mi][ni], 0, 0, 0);
                acc[mi][ni] = __builtin_amdgcn_mfma_f32_16x16x32_bf16(
                    ah, bl[ni], acc[mi][ni], 0, 0, 0);
                acc[mi][ni] = __builtin_amdgcn_mfma_f32_16x16x32_bf16(
                    al, bh[ni], acc[mi][ni], 0, 0, 0);
            }
        }
    };
    auto bar = [&]() {
        asm volatile("s_waitcnt lgkmcnt(0)" ::: "memory");
        __builtin_amdgcn_s_barrier();
    };

    float4 paA[NA], paB[NA];
    bf16x8 bh[FN], bl[FN];

    loadA(k0, paA);
    loadB(k0, bh, bl);
    loadA(k0 + BK, paB);
    storeA(Ah0, Al0, paA);
    bar();

    for (int t = 0; t < nit; t += 2) {
        // phase A: compute tile t from buf0
        if (t + 2 < nit) loadA(k0 + (t + 2) * BK, paA);
        mmaStep(Ah0, Al0, bh, bl);
        if (t + 1 < nit) loadB(k0 + (t + 1) * BK, bh, bl);  // after consumption
        storeA(Ah1, Al1, paB);
        bar();
        // phase B: compute tile t+1 from buf1
        if (t + 3 < nit) loadA(k0 + (t + 3) * BK, paB);
        mmaStep(Ah1, Al1, bh, bl);
        if (t + 2 < nit) {
            loadB(k0 + (t + 2) * BK, bh, bl);
            storeA(Ah0, Al0, paA);
            bar();
        }
    }

    float bv[FN];
#pragma unroll
    for (int ni = 0; ni < FN; ++ni)
        bv[ni] = (bias && ks == 0)
               ? bias[(long)zb * sBias + n0 + wn + ni * 16 + lr] : 0.f;
    const int cr = (lane >> 4) * 4;
#pragma unroll
    for (int mi = 0; mi < FM; ++mi)
#pragma unroll
        for (int ni = 0; ni < FN; ++ni) {
#pragma unroll
            for (int r = 0; r < 4; ++r) {
                float t = acc[mi][ni][r] * alpha + bv[ni];
                if (ACT == 1) t = fmaxf(t, 0.f);
                else if (ACT == 2) t = tanhf(t);
                Cbase[(long)(m0 + wm + mi * 16 + cr + r) * ldc
                      + n0 + wn + ni * 16 + lr] = t;
            }
        }
}

// ---------------------------------------------------------------------------
// Dynamic-B split-bf16 MFMA GEMM (QK^T and PV; BT=true).
// MODE: 0 = full; 1 = QK^T band skip; 2 = PV banded K-range.
// ---------------------------------------------------------------------------
template<int BM, int BN, int ACT, bool BT, int MODE>
__global__ __launch_bounds__(256)
void gemm_mfma(const float* __restrict__ A, int lda, long sA,
               const float* __restrict__ B, int ldb, long sB,
               float* __restrict__ C, int ldc, long sC,
               const float* __restrict__ bias, long sBias,
               int K, float alpha, const int* __restrict__ winp)
{
    constexpr int BK = 32;
    constexpr int PK = 40;
    constexpr int FM = BM / 32;
    constexpr int FN = BN / 32;
    constexpr int NA = BM / 32;
    constexpr int NB = BN / 32;

    __shared__ __align__(16) unsigned short Ah[BM][PK], Al[BM][PK];
    __shared__ __align__(16) unsigned short Bh[BN][PK], Bl[BN][PK];

    int bx, by, bz;
    xcd_decode(bx, by, bz);

    const int n0 = bx * BN;
    const int m0 = by * BM;

    int klo = 0, khi = K;
    if constexpr (MODE == 1) {
        const int w = winp[0];
        if (n0 > m0 + (BM - 1) + w || m0 > n0 + (BN - 1) + w) return;
    } else if constexpr (MODE == 2) {
        const int w = winp[0];
        klo = (m0 > w) ? ((m0 - w) & ~31) : 0;
        khi = (m0 + BM + w + 31) & ~31;
        if (khi > K) khi = K;
    }

    const int tid  = threadIdx.x;
    const int lane = tid & 63;
    const int wave = tid >> 6;
    const int wm   = (wave >> 1) * (BM / 2);
    const int wn   = (wave & 1)  * (BN / 2);
    const int lr   = lane & 15;
    const int ko   = (lane >> 4) * 8;

    const float* Abase = A + (long)bz * sA;
    const float* Bbase = B + (long)bz * sB;
    float*       Cbase = C + (long)bz * sC;

    f32x4 acc[FM][FN];
#pragma unroll
    for (int i = 0; i < FM; ++i)
#pragma unroll
        for (int j = 0; j < FN; ++j) acc[i][j] = f32x4{0.f, 0.f, 0.f, 0.f};

    const int akq = tid & 7;
    const int amr = tid >> 3;

    auto loadA = [&](int kt, float4* pa) {
#pragma unroll
        for (int r = 0; r < NA; ++r)
            pa[r] = *(const float4*)(Abase + (long)(m0 + r * 32 + amr) * lda + kt + akq * 4);
    };
    auto loadB = [&](int kt, float4* pb) {
#pragma unroll
        for (int r = 0; r < NB; ++r)
            pb[r] = *(const float4*)(Bbase + (long)(n0 + r * 32 + amr) * ldb + kt + akq * 4);
    };
    auto storeA = [&](const float4* pa) {
#pragma unroll
        for (int r = 0; r < NA; ++r) {
            ushort4 h, l;
            split1(pa[r].x, h.x, l.x); split1(pa[r].y, h.y, l.y);
            split1(pa[r].z, h.z, l.z); split1(pa[r].w, h.w, l.w);
            *(ushort4*)&Ah[r * 32 + amr][akq * 4] = h;
            *(ushort4*)&Al[r * 32 + amr][akq * 4] = l;
        }
    };
    auto storeB = [&](const float4* pb) {
#pragma unroll
        for (int r = 0; r < NB; ++r) {
            ushort4 h, l;
            split1(pb[r].x, h.x, l.x); split1(pb[r].y, h.y, l.y);
            split1(pb[r].z, h.z, l.z); split1(pb[r].w, h.w, l.w);
            *(ushort4*)&Bh[r * 32 + amr][akq * 4] = h;
            *(ushort4*)&Bl[r * 32 + amr][akq * 4] = l;
        }
    };

    float4 pa[NA], pb[NB];
    loadA(klo, pa); loadB(klo, pb);

    for (int kt = klo; kt < khi; kt += BK) {
        storeA(pa);
        storeB(pb);
        __syncthreads();

        const bool more = kt + BK < khi;
        float4 na[NA], nb[NB];
        if (more) { loadA(kt + BK, na); loadB(kt + BK, nb); }

        bf16x8 ah[FM], al[FM], bh[FN], bl[FN];
#pragma unroll
        for (int mi = 0; mi < FM; ++mi) {
            ah[mi] = *(const bf16x8*)&Ah[wm + mi * 16 + lr][ko];
            al[mi] = *(const bf16x8*)&Al[wm + mi * 16 + lr][ko];
        }
#pragma unroll
        for (int ni = 0; ni < FN; ++ni) {
            bh[ni] = *(const bf16x8*)&Bh[wn + ni * 16 + lr][ko];
            bl[ni] = *(const bf16x8*)&Bl[wn + ni * 16 + lr][ko];
        }
#pragma unroll
        for (int mi = 0; mi < FM; ++mi)
#pragma unroll
            for (int ni = 0; ni < FN; ++ni) {
                acc[mi][ni] = __builtin_amdgcn_mfma_f32_16x16x32_bf16(
                    ah[mi], bh[ni], acc[mi][ni], 0, 0, 0);
                acc[mi][ni] = __builtin_amdgcn_mfma_f32_16x16x32_bf16(
                    ah[mi], bl[ni], acc[mi][ni], 0, 0, 0);
                acc[mi][ni] = __builtin_amdgcn_mfma_f32_16x16x32_bf16(
                    al[mi], bh[ni], acc[mi][ni], 0, 0, 0);
            }
        __syncthreads();

        if (more) {
#pragma unroll
            for (int r = 0; r < NA; ++r) pa[r] = na[r];
#pragma unroll
            for (int r = 0; r < NB; ++r) pb[r] = nb[r];
        }
    }

    float bv[FN];
#pragma unroll
    for (int ni = 0; ni < FN; ++ni)
        bv[ni] = bias ? bias[(long)bz * sBias + n0 + wn + ni * 16 + lr] : 0.f;
    const int cr = (lane >> 4) * 4;
#pragma unroll
    for (int mi = 0; mi < FM; ++mi)
#pragma unroll
        for (int ni = 0; ni < FN; ++ni) {
#pragma unroll
            for (int r = 0; r < 4; ++r) {
                float t = acc[mi][ni][r] * alpha + bv[ni];
                if (ACT == 1) t = fmaxf(t, 0.f);
                else if (ACT == 2) t = tanhf(t);
                Cbase[(long)(m0 + wm + mi * 16 + cr + r) * ldc
                      + n0 + wn + ni * 16 + lr] = t;
            }
        }
}

// ---------------------------------------------------------------------------
// vt[b][c][l] = qkv[b][l][2048 + c]
// ---------------------------------------------------------------------------
__global__ __launch_bounds__(256)
void vtrans_kernel(const float* __restrict__ qkv, float* __restrict__ vt)
{
    __shared__ float t[32][33];
    const int b  = blockIdx.z;
    const int l0 = blockIdx.x * 32, c0 = blockIdx.y * 32;
    const int tx = threadIdx.x & 31, ty = threadIdx.x >> 5;
    const float* src = qkv + (long)b * 3 * LD + 2048;
#pragma unroll
    for (int r = ty; r < 32; r += 8)
        t[r][tx] = src[(long)(l0 + r) * 3072 + c0 + tx];
    __syncthreads();
    float* dst = vt + (long)b * LD;
#pragma unroll
    for (int r = ty; r < 32; r += 8)
        dst[(long)(c0 + r) * L + l0 + tx] = t[tx][r];
}

// ---------------------------------------------------------------------------
__global__ void add_pe_kernel(const float* __restrict__ src, float* __restrict__ x)
{
    long idx = (long)blockIdx.x * 256 + threadIdx.x;   // < LD
    int pos = (int)(idx >> 10);
    int d   = (int)(idx & 1023);
    float expnt = (float)(d & ~1) * (1.0f / (float)D);
    float denom = powf(10000.0f, expnt);
    float ang   = (float)pos / denom;
    float pe    = (d & 1) ? cosf(ang) : sinf(ang);
    float v = src[idx] + pe;
    x[idx]          = v;
    x[LD + idx]     = v;
    x[2 * LD + idx] = v;
}

// ---------------------------------------------------------------------------
// Banded masked softmax (see R5 comments; select semantics keep unwritten
// S tiles harmless).
// ---------------------------------------------------------------------------
__global__ __launch_bounds__(256)
void softmax_mask_kernel(float* __restrict__ S, const int* __restrict__ utt,
                         const int* __restrict__ spk, const int* __restrict__ winp,
                         int branch)
{
    __shared__ float red[8];
    const int i   = blockIdx.x;
    const int h   = blockIdx.y;
    const int tid = threadIdx.x;
    float* row = S + ((long)h * L + i) * L;
    const int w    = winp[0];
    const int ti   = i >> 6;
    const int kmin = (ti * 64 > w) ? (((ti * 64 - w) >> 5) << 5) : 0;
    int khi = (ti * 64 + 64 + w + 31) & ~31;
    if (khi > L) khi = L;
    const int utti = utt[i];
    const int spki = spk[i];
    const int j0 = kmin + tid * 4;
    const bool act = j0 < khi;

    float s[4] = {-1e9f, -1e9f, -1e9f, -1e9f};
    if (act) {
        float4 sv = *(float4*)(row + j0);
        float svv[4] = {sv.x, sv.y, sv.z, sv.w};
#pragma unroll
        for (int c = 0; c < 4; ++c) {
            int j = j0 + c;
            int dd = j - i;
            bool win  = (dd <= w) && (-dd <= w);
            bool base = win && (utti > 0) && (utt[j] > 0);
            bool same = (spk[j] == spki);
            bool keep = (branch == 0) ? base
                      : (branch == 1) ? (base && same)
                      : (base && (!same || (j == i)));
            s[c] = keep ? svv[c] : -1e9f;
        }
    }
    float mx = fmaxf(fmaxf(s[0], s[1]), fmaxf(s[2], s[3]));
    for (int off = 32; off; off >>= 1) mx = fmaxf(mx, __shfl_xor(mx, off));
    if ((tid & 63) == 0) red[tid >> 6] = mx;
    __syncthreads();
    mx = fmaxf(fmaxf(red[0], red[1]), fmaxf(red[2], red[3]));
    __syncthreads();

    float e[4]; float sum = 0.f;
#pragma unroll
    for (int c = 0; c < 4; ++c) { e[c] = expf(s[c] - mx); sum += e[c]; }
    for (int off = 32; off; off >>= 1) sum += __shfl_xor(sum, off);
    if ((tid & 63) == 0) red[tid >> 6] = sum;
    __syncthreads();
    float inv = 1.f / (red[0] + red[1] + red[2] + red[3]);

    if (act) {
        float4 o = {e[0] * inv, e[1] * inv, e[2] * inv, e[3] * inv};
        *(float4*)(row + j0) = o;
    }
}

// ---------------------------------------------------------------------------
// LayerNorm: out = LN(x + sum_{s<nslc} r[s]) * g + b
// ---------------------------------------------------------------------------
__global__ __launch_bounds__(256)
void ln_kernel(const float* __restrict__ x, const float* __restrict__ r,
               int nslc, long sSlice,
               const float* __restrict__ g, const float* __restrict__ b,
               float* __restrict__ out, long paramStride)
{
    __shared__ float red[8];
    const int row = blockIdx.x;
    const int grp = row >> 10;
    const int tid = threadIdx.x;
    const long base = (long)row * D + tid * 4;

    float4 t = *(const float4*)(x + base);
    for (int s = 0; s < nslc; ++s) {
        float4 rv = *(const float4*)(r + (long)s * sSlice + base);
        t.x += rv.x; t.y += rv.y; t.z += rv.z; t.w += rv.w;
    }

    float sm = t.x + t.y + t.z + t.w;
    for (int off = 32; off; off >>= 1) sm += __shfl_xor(sm, off);
    if ((tid & 63) == 0) red[tid >> 6] = sm;
    __syncthreads();
    float mean = (red[0] + red[1] + red[2] + red[3]) * (1.f / (float)D);
    __syncthreads();

    float4 dv = {t.x - mean, t.y - mean, t.z - mean, t.w - mean};
    float sq = dv.x * dv.x + dv.y * dv.y + dv.z * dv.z + dv.w * dv.w;
    for (int off = 32; off; off >>= 1) sq += __shfl_xor(sq, off);
    if ((tid & 63) == 0) red[tid >> 6] = sq;
    __syncthreads();
    float var  = (red[0] + red[1] + red[2] + red[3]) * (1.f / (float)D);
    float rstd = rsqrtf(var + 1e-5f);

    const float* gp = g + (long)grp * paramStride + tid * 4;
    const float* bp = b + (long)grp * paramStride + tid * 4;
    float4 gv = *(const float4*)gp;
    float4 bv = *(const float4*)bp;
    float4 o = {dv.x * rstd * gv.x + bv.x, dv.y * rstd * gv.y + bv.y,
                dv.z * rstd * gv.z + bv.z, dv.w * rstd * gv.w + bv.w};
    *(float4*)(out + base) = o;
}

// ---------------------------------------------------------------------------
// s[row] = dot(tanh(sum_slices t[row]), v); rows = 2*L
// ---------------------------------------------------------------------------
__global__ __launch_bounds__(256)
void rowdot_kernel(const float* __restrict__ t, long sSlice, int nslc,
                   const float* __restrict__ v, float* __restrict__ s)
{
    __shared__ float red[8];
    const int row = blockIdx.x;
    const int tid = threadIdx.x;
    const long base = (long)row * D + tid * 4;
    float4 a = *(const float4*)(t + base);
    for (int sl = 1; sl < nslc; ++sl) {
        float4 a2 = *(const float4*)(t + (long)sl * sSlice + base);
        a.x += a2.x; a.y += a2.y; a.z += a2.z; a.w += a2.w;
    }
    a.x = tanhf(a.x); a.y = tanhf(a.y); a.z = tanhf(a.z); a.w = tanhf(a.w);
    float4 vv = *(const float4*)(v + tid * 4);
    float p = a.x * vv.x + a.y * vv.y + a.z * vv.z + a.w * vv.w;
    for (int off = 32; off; off >>= 1) p += __shfl_xor(p, off);
    if ((tid & 63) == 0) red[tid >> 6] = p;
    __syncthreads();
    if (tid == 0) s[row] = red[0] + red[1] + red[2] + red[3];
}

// ---------------------------------------------------------------------------
__global__ void combine_kernel(const float* __restrict__ sb, const float* __restrict__ h,
                               float* __restrict__ out)
{
    long idx = (long)blockIdx.x * 256 + threadIdx.x;   // < LD
    int l = (int)(idx >> 10);
    float s0 = sb[l], s1 = sb[L + l];
    float m  = fmaxf(s0, s1);
    float e0 = expf(s0 - m), e1 = expf(s1 - m);
    float inv = 1.f / (e0 + e1);
    out[idx] = (e0 * h[idx] + e1 * h[LD + idx]) * inv;
}

// ---------------------------------------------------------------------------
__global__ __launch_bounds__(256)
void cls_kernel(const float* __restrict__ x, const float* __restrict__ W,
                const float* __restrict__ b, float* __restrict__ out)
{
    __shared__ float red[4][7];
    __shared__ float logit[7];
    const int row = blockIdx.x;
    const int tid = threadIdx.x;
    float p[7] = {0, 0, 0, 0, 0, 0, 0};
    for (int d = tid; d < D; d += 256) {
        float xv = x[(long)row * D + d];
#pragma unroll
        for (int c = 0; c < 7; ++c) p[c] = fmaf(xv, W[d * 7 + c], p[c]);
    }
#pragma unroll
    for (int c = 0; c < 7; ++c) {
        float v = p[c];
        for (int off = 32; off; off >>= 1) v += __shfl_xor(v, off);
        if ((tid & 63) == 0) red[tid >> 6][c] = v;
    }
    __syncthreads();
    if (tid < 7)
        logit[tid] = red[0][tid] + red[1][tid] + red[2][tid] + red[3][tid] + b[tid];
    __syncthreads();
    if (tid == 0) {
        float mx = logit[0];
        for (int c = 1; c < 7; ++c) mx = fmaxf(mx, logit[c]);
        float sum = 0.f;
        for (int c = 0; c < 7; ++c) sum += expf(logit[c] - mx);
        float lse = logf(sum) + mx;
        for (int c = 0; c < 7; ++c) out[(long)row * 7 + c] = logit[c] - lse;
    }
}

} // anonymous namespace

extern "C" void kernel_launch(void* const* d_in, const int* in_sizes, int n_in,
                              void* d_out, int out_size, void* d_ws, size_t ws_size,
                              hipStream_t stream)
{
    (void)in_sizes; (void)n_in; (void)out_size; (void)ws_size;

    const float* src  = (const float*)d_in[0];
    const int*   utt  = (const int*)d_in[1];
    const int*   spk  = (const int*)d_in[2];
    const int*   winp = (const int*)d_in[3];
    const float* Wqkv = (const float*)d_in[4];
    const float* bqkv = (const float*)d_in[5];
    const float* Wo   = (const float*)d_in[6];
    const float* bo   = (const float*)d_in[7];
    const float* g1   = (const float*)d_in[8];
    const float* b1   = (const float*)d_in[9];
    const float* Wf1  = (const float*)d_in[10];
    const float* bf1  = (const float*)d_in[11];
    const float* Wf2  = (const float*)d_in[12];
    const float* bf2  = (const float*)d_in[13];
    const float* g2   = (const float*)d_in[14];
    const float* b2   = (const float*)d_in[15];
    const float* f1W  = (const float*)d_in[16];
    const float* f1b  = (const float*)d_in[17];
    const float* f1v  = (const float*)d_in[18];
    const float* f2W  = (const float*)d_in[19];
    const float* f2b  = (const float*)d_in[20];
    const float* f2v  = (const float*)d_in[21];
    const float* clsW = (const float*)d_in[22];
    const float* clsb = (const float*)d_in[23];
    float* out = (float*)d_out;

    // ---- workspace arena (floats) ----
    float* ws    = (float*)d_ws;
    float* x     = ws;               // 3*LD
    float* qkv   = x + 3 * LD;       // 9*LD ; later FFN2 slice scratch
    float* attno = qkv + 9 * LD;     // 3*LD
    float* tmp   = attno + 3 * LD;   // 3*LD ; vt during attention; fusion out
    float* R1    = tmp + 3 * LD;     // 16*LD  S / slices / ffn
    float* sbuf  = R1 + 16 * LD;     // 2*L
    float* S    = R1;                // [16][L][L] scores (attention phase)
    float* ffn  = R1;                // [3][L][DFF] (FFN phase)
    float* vt   = tmp;               // [3][D][L] transposed V (attention phase)
    float* f2s  = qkv;               // [4][3][L][D] FFN2 slices
    float* h2   = R1 + 4 * LD;       // [2][L][D] (fusion phase)
    unsigned short* wpack = (unsigned short*)(sbuf + 2 * L);

    add_pe_kernel<<<LD / 256, 256, 0, stream>>>(src, x);

    for (int l = 0; l < NL; ++l) {
        // QKV projection: repack (32x24 tiles) + wide-N GEMM (grid 288)
        repack_w<<<dim3(32 * 24, 3), 256, 0, stream>>>(
            Wqkv + (long)l * D * 3 * D, 3 * D, (long)NL * D * 3 * D,
            wpack, (long)2 * D * 3 * D, 3 * D);
        gemm_mfma_pb<128, 256, 0>
            <<<dim3(3 * D / 256, L / 128, 3), 256, 0, stream>>>(
            x, D, LD, wpack, 3 * D, (long)2 * D * 3 * D,
            qkv, 3 * D, 3 * LD, bqkv + (long)l * 3 * D, (long)NL * 3 * D,
            D, 1.f, 1, 0);

        vtrans_kernel<<<dim3(L / 32, D / 32, 3), 256, 0, stream>>>(qkv, vt);

        for (int b = 0; b < 3; ++b) {
            const float* qkvb = qkv + (long)b * 3 * LD;
            // scores: banded QK^T (skips fully-masked 128x128 tiles)
            gemm_mfma<128, 128, 0, true, 1>
                <<<dim3(L / 128, L / 128, NH), 256, 0, stream>>>(
                qkvb, 3 * D, 64, qkvb + D, 3 * D, 64,
                S, L, (long)L * L, nullptr, 0, DH, 0.125f, winp);
            softmax_mask_kernel<<<dim3(L, NH), 256, 0, stream>>>(S, utt, spk, winp, b);
            // O = P @ V^T-rows, banded K-range (exact: P==0 outside band)
            gemm_mfma<64, 64, 0, true, 2>
                <<<dim3(1, L / 64, NH), 256, 0, stream>>>(
                S, L, (long)L * L, vt + (long)b * LD, L, (long)64 * L,
                attno + (long)b * LD, D, 64, nullptr, 0, L, 1.f, winp);
        }

        // output projection, split-K=4 (grid 384)
        repack_w<<<dim3(32 * 8, 3), 256, 0, stream>>>(
            Wo + (long)l * D * D, D, (long)NL * D * D,
            wpack, (long)2 * D * D, D);
        gemm_mfma_pb<128, 256, 0>
            <<<dim3(D / 256, L / 128, 12), 256, 0, stream>>>(
            attno, D, LD, wpack, D, (long)2 * D * D,
            R1, D, LD, bo + (long)l * D, (long)NL * D,
            D, 1.f, 4, (long)3 * LD);
        ln_kernel<<<3 * L, 256, 0, stream>>>(x, R1, 4, (long)3 * LD,
                                             g1 + (long)l * D, b1 + (long)l * D,
                                             x, (long)NL * D);
        // FFN1 (relu, grid 384)
        repack_w<<<dim3(32 * 32, 3), 256, 0, stream>>>(
            Wf1 + (long)l * D * DFF, DFF, (long)NL * D * DFF,
            wpack, (long)2 * D * DFF, DFF);
        gemm_mfma_pb<128, 256, 1>
            <<<dim3(DFF / 256, L / 128, 3), 256, 0, stream>>>(
            x, D, LD, wpack, DFF, (long)2 * D * DFF,
            ffn, DFF, (long)L * DFF, bf1 + (long)l * DFF, (long)NL * DFF,
            D, 1.f, 1, 0);
        // FFN2, split-K=4 (grid 384)
        repack_w<<<dim3(128 * 8, 3), 256, 0, stream>>>(
            Wf2 + (long)l * DFF * D, D, (long)NL * DFF * D,
            wpack, (long)2 * DFF * D, D);
        gemm_mfma_pb<128, 256, 0>
            <<<dim3(D / 256, L / 128, 12), 256, 0, stream>>>(
            ffn, DFF, (long)L * DFF, wpack, D, (long)2 * DFF * D,
            f2s, D, LD, bf2 + (long)l * D, (long)NL * D,
            DFF, 1.f, 4, (long)3 * LD);
        ln_kernel<<<3 * L, 256, 0, stream>>>(x, f2s, 4, (long)3 * LD,
                                             g2 + (long)l * D, b2 + (long)l * D,
                                             x, (long)NL * D);
    }

    // ---- fusion 1 ----
    repack_w<<<dim3(32 * 8, 1), 256, 0, stream>>>(f1W, D, 0, wpack, 0, D);
    gemm_mfma_pb<128, 256, 0>
        <<<dim3(D / 256, L / 128, 4), 256, 0, stream>>>(
        x + LD, D, LD, wpack, D, 0, R1, D, LD, f1b, 0, D, 1.f, 2, (long)2 * LD);
    rowdot_kernel<<<2 * L, 256, 0, stream>>>(R1, (long)2 * LD, 2, f1v, sbuf);
    combine_kernel<<<LD / 256, 256, 0, stream>>>(sbuf, x + LD, h2 + LD);   // sp -> h2[1]
    hipMemcpyAsync(h2, x, LD * sizeof(float), hipMemcpyDeviceToDevice, stream); // ct

    // ---- fusion 2 ----
    repack_w<<<dim3(32 * 8, 1), 256, 0, stream>>>(f2W, D, 0, wpack, 0, D);
    gemm_mfma_pb<128, 256, 0>
        <<<dim3(D / 256, L / 128, 4), 256, 0, stream>>>(
        h2, D, LD, wpack, D, 0, R1, D, LD, f2b, 0, D, 1.f, 2, (long)2 * LD);
    rowdot_kernel<<<2 * L, 256, 0, stream>>>(R1, (long)2 * LD, 2, f2v, sbuf);
    combine_kernel<<<LD / 256, 256, 0, stream>>>(sbuf, h2, tmp);           // fused -> tmp

    // ---- classifier + log_softmax ----
    cls_kernel<<<L, 256, 0, stream>>>(tmp, clsW, clsb, out);
}